// Round 1
// baseline (6170.897 us; speedup 1.0000x reference)
//
#include <hip/hip_runtime.h>
#include <hip/hip_bf16.h>
#include <math.h>

// Problem constants
#define B_  4
#define T_  1024
#define IN_ 256
#define H_  512
#define L_  4
#define Di_ 1024
#define S_  16
#define R_  32
#define KC_ 4
#define OUT_ 256
#define M_  (B_*T_)          // 4096 rows everywhere

#define RMS_EPS 1.1920929e-07f
#define LN_EPS  1e-05f

// ---------------------------------------------------------------------------
// prep: nan_to_num + per-row nan mask (x: (M, IN_)), block = 256 = IN_
// ---------------------------------------------------------------------------
__global__ __launch_bounds__(256) void prep_kernel(const float* __restrict__ x,
                                                   float* __restrict__ xclean,
                                                   float* __restrict__ mask) {
    int row = blockIdx.x;
    int tid = threadIdx.x;
    float v = x[(size_t)row * IN_ + tid];
    int isn = isnan(v) ? 1 : 0;
    xclean[(size_t)row * IN_ + tid] = isn ? 0.f : v;
    __shared__ int f;
    if (tid == 0) f = 0;
    __syncthreads();
    if (isn) f = 1;
    __syncthreads();
    if (tid == 0) mask[row] = f ? 0.f : 1.f;
}

// ---------------------------------------------------------------------------
// Generic f32 GEMM:  C[m,n] (+)= act( A[m,:k] . W[n,:k] + bias[n] ) * rowmask[m]
// A: (M,K) row stride lda ; W: (N,K) row stride ldw ; C row stride ldc.
// 64x64 tile, BK=16, 256 threads, 4x4 micro-tile. M,N % 64 == 0, K % 16 == 0.
// act: 0 = none, 1 = softplus
// ---------------------------------------------------------------------------
#define LDSP 68   // padded LDS row stride (floats): multiple of 4 -> aligned b128
template<bool ACC>
__global__ __launch_bounds__(256) void gemm_nt(const float* __restrict__ A, int lda,
                                               const float* __restrict__ W, int ldw,
                                               float* __restrict__ C, int ldc,
                                               int K,
                                               const float* __restrict__ bias,
                                               const float* __restrict__ rowmask,
                                               int act) {
    __shared__ float As[16 * LDSP];
    __shared__ float Ws[16 * LDSP];
    const int bm = blockIdx.y * 64;
    const int bn = blockIdx.x * 64;
    const int tid = threadIdx.x;
    const int ty = tid >> 4;   // 0..15 -> C rows ty*4..ty*4+3
    const int tx = tid & 15;   // 0..15 -> C cols tx*4..tx*4+3

    float acc[4][4] = {};

    for (int k0 = 0; k0 < K; k0 += 16) {
        #pragma unroll
        for (int i = 0; i < 4; ++i) {
            int idx = tid + i * 256;           // 0..1023
            int r = idx >> 4, kk = idx & 15;   // tile row, tile k
            As[kk * LDSP + r] = A[(size_t)(bm + r) * lda + k0 + kk];
            Ws[kk * LDSP + r] = W[(size_t)(bn + r) * ldw + k0 + kk];
        }
        __syncthreads();
        #pragma unroll
        for (int kk = 0; kk < 16; ++kk) {
            float4 av = *reinterpret_cast<const float4*>(&As[kk * LDSP + ty * 4]);
            float4 bv = *reinterpret_cast<const float4*>(&Ws[kk * LDSP + tx * 4]);
            float a[4] = {av.x, av.y, av.z, av.w};
            float b[4] = {bv.x, bv.y, bv.z, bv.w};
            #pragma unroll
            for (int i = 0; i < 4; ++i)
                #pragma unroll
                for (int j = 0; j < 4; ++j)
                    acc[i][j] = fmaf(a[i], b[j], acc[i][j]);
        }
        __syncthreads();
    }

    #pragma unroll
    for (int i = 0; i < 4; ++i) {
        int m = bm + ty * 4 + i;
        float rm = rowmask ? rowmask[m] : 1.f;
        #pragma unroll
        for (int j = 0; j < 4; ++j) {
            int n = bn + tx * 4 + j;
            float v = acc[i][j];
            if (bias) v += bias[n];
            if (act == 1) v = (v > 20.f) ? v : log1pf(__expf(v));
            v *= rm;
            float* p = &C[(size_t)m * ldc + n];
            if (ACC) v += *p;
            *p = v;
        }
    }
}

// ---------------------------------------------------------------------------
// RMSNorm over last dim H_=512. One block (256 thr) per row.
// ---------------------------------------------------------------------------
__global__ __launch_bounds__(256) void rms_norm_kernel(const float* __restrict__ h,
                                                       const float* __restrict__ w,
                                                       float* __restrict__ xn) {
    int row = blockIdx.x, tid = threadIdx.x;
    const float* hr = h + (size_t)row * H_;
    float v0 = hr[tid], v1 = hr[tid + 256];
    float s = v0 * v0 + v1 * v1;
    #pragma unroll
    for (int off = 32; off > 0; off >>= 1) s += __shfl_down(s, off);
    __shared__ float red[4];
    int wid = tid >> 6, lane = tid & 63;
    if (lane == 0) red[wid] = s;
    __syncthreads();
    float tot = red[0] + red[1] + red[2] + red[3];
    float sc = rsqrtf(tot * (1.f / H_) + RMS_EPS);
    xn[(size_t)row * H_ + tid]       = v0 * sc * w[tid];
    xn[(size_t)row * H_ + tid + 256] = v1 * sc * w[tid + 256];
}

// ---------------------------------------------------------------------------
// LayerNorm over last dim H_=512 (two-pass). One block per row.
// ---------------------------------------------------------------------------
__global__ __launch_bounds__(256) void layer_norm_kernel(const float* __restrict__ h,
                                                         const float* __restrict__ g,
                                                         const float* __restrict__ bb,
                                                         float* __restrict__ out) {
    int row = blockIdx.x, tid = threadIdx.x;
    const float* hr = h + (size_t)row * H_;
    float v0 = hr[tid], v1 = hr[tid + 256];
    float s = v0 + v1;
    #pragma unroll
    for (int off = 32; off > 0; off >>= 1) s += __shfl_down(s, off);
    __shared__ float red[4];
    int wid = tid >> 6, lane = tid & 63;
    if (lane == 0) red[wid] = s;
    __syncthreads();
    float mu = (red[0] + red[1] + red[2] + red[3]) * (1.f / H_);
    __syncthreads();
    float d0 = v0 - mu, d1 = v1 - mu;
    float q = d0 * d0 + d1 * d1;
    #pragma unroll
    for (int off = 32; off > 0; off >>= 1) q += __shfl_down(q, off);
    if (lane == 0) red[wid] = q;
    __syncthreads();
    float var = (red[0] + red[1] + red[2] + red[3]) * (1.f / H_);
    float sc = rsqrtf(var + LN_EPS);
    out[(size_t)row * H_ + tid]       = d0 * sc * g[tid]       + bb[tid];
    out[(size_t)row * H_ + tid + 256] = d1 * sc * g[tid + 256] + bb[tid + 256];
}

// ---------------------------------------------------------------------------
// Causal depthwise conv (K=4, left-pad 3) + SiLU.
// xx = xz[..., :Di_] of xz (M, 2*Di_).  u: (M, Di_).
// ---------------------------------------------------------------------------
__global__ __launch_bounds__(256) void conv_silu_kernel(const float* __restrict__ xz,
                                                        const float* __restrict__ cw,
                                                        const float* __restrict__ cb,
                                                        float* __restrict__ u) {
    int idx = blockIdx.x * 256 + threadIdx.x;     // 0 .. M_*Di_-1
    int c  = idx & (Di_ - 1);
    int bt = idx >> 10;                            // Di_ = 1024
    int t  = bt & (T_ - 1);
    const float* base = xz + (size_t)bt * (2 * Di_) + c;
    float w0 = cw[c * KC_ + 0], w1 = cw[c * KC_ + 1];
    float w2 = cw[c * KC_ + 2], w3 = cw[c * KC_ + 3];
    float acc = cb[c];
    acc += base[0] * w3;
    if (t >= 1) acc += base[-(1 * 2 * Di_)] * w2;
    if (t >= 2) acc += base[-(2 * 2 * Di_)] * w1;
    if (t >= 3) acc += base[-(3 * 2 * Di_)] * w0;
    u[idx] = acc * (1.f / (1.f + __expf(-acc)));   // silu
}

// ---------------------------------------------------------------------------
// Selective scan. One thread per (b, channel); 16 blocks x 256 threads.
// Reads delta (M,Di), u (M,Di), B/C from xd (M,64) cols 32..63, z from xz.
// Writes y (M,Di) — y may alias u (element-wise in-place is safe).
// ---------------------------------------------------------------------------
__global__ __launch_bounds__(256) void scan_kernel(const float* __restrict__ delta,
                                                   const float* __restrict__ u_in,
                                                   const float* __restrict__ xd,
                                                   const float* __restrict__ xz,
                                                   const float* __restrict__ A_log,
                                                   const float* __restrict__ D_ssm,
                                                   float* __restrict__ y_out) {
    int blk = blockIdx.x;            // 0..15
    int b = blk >> 2;                // 4 blocks per batch
    int c = ((blk & 3) << 8) + threadIdx.x;   // channel 0..1023

    float Ac[S_];
    #pragma unroll
    for (int s = 0; s < S_; ++s) Ac[s] = -__expf(A_log[c * S_ + s]);
    float Dp = D_ssm[c];
    float hst[S_] = {};

    __shared__ float bc[2 * S_];
    const size_t base_bt = (size_t)b * T_;

    for (int t = 0; t < T_; ++t) {
        size_t bt = base_bt + t;
        __syncthreads();
        if (threadIdx.x < 2 * S_) bc[threadIdx.x] = xd[bt * 64 + R_ + threadIdx.x];
        __syncthreads();
        float d  = delta[bt * Di_ + c];
        float uu = u_in[bt * Di_ + c];
        float du = d * uu;
        float y = 0.f;
        #pragma unroll
        for (int s = 0; s < S_; ++s) {
            hst[s] = hst[s] * __expf(d * Ac[s]) + du * bc[s];
            y = fmaf(hst[s], bc[S_ + s], y);
        }
        y += uu * Dp;
        float zz = xz[bt * (2 * Di_) + Di_ + c];
        float sig = 1.f / (1.f + __expf(-zz));
        y_out[bt * Di_ + c] = y * (zz * sig);
    }
}

// ---------------------------------------------------------------------------
// Host launch
// ---------------------------------------------------------------------------
extern "C" void kernel_launch(void* const* d_in, const int* in_sizes, int n_in,
                              void* d_out, int out_size, void* d_ws, size_t ws_size,
                              hipStream_t stream) {
    const float* x         = (const float*)d_in[0];
    const float* in_w      = (const float*)d_in[1];
    const float* in_b      = (const float*)d_in[2];
    const float* rms_w     = (const float*)d_in[3];
    const float* in_proj_w = (const float*)d_in[4];
    const float* conv_w    = (const float*)d_in[5];
    const float* conv_b    = (const float*)d_in[6];
    const float* x_proj_w  = (const float*)d_in[7];
    const float* dt_proj_w = (const float*)d_in[8];
    const float* dt_proj_b = (const float*)d_in[9];
    const float* A_log     = (const float*)d_in[10];
    const float* D_ssm     = (const float*)d_in[11];
    const float* mb_out_w  = (const float*)d_in[12];
    const float* ln_g      = (const float*)d_in[13];
    const float* ln_b      = (const float*)d_in[14];
    const float* out_w     = (const float*)d_in[15];
    const float* out_b     = (const float*)d_in[16];

    float* ws = (float*)d_ws;
    // workspace layout (floats)
    float* h      = ws;                       // M*H            = 2,097,152
    float* xn     = h      + (size_t)M_ * H_;         // 2,097,152
    float* xz     = xn     + (size_t)M_ * H_;         // M*2Di = 8,388,608
    float* u      = xz     + (size_t)M_ * 2 * Di_;    // M*Di  = 4,194,304
    float* xd     = u      + (size_t)M_ * Di_;        // M*64  =   262,144
    float* delta  = xd     + (size_t)M_ * 64;         // M*Di  = 4,194,304
    float* xclean = delta;                             // alias: needs M*IN <= M*Di
    float* mask   = delta  + (size_t)M_ * Di_;        // M
    (void)ws_size; (void)n_in; (void)in_sizes; (void)out_size;

    // 1) nan handling
    prep_kernel<<<M_, 256, 0, stream>>>(x, xclean, mask);

    // 2) h = (xclean @ in_w.T + in_b) * mask
    gemm_nt<false><<<dim3(H_ / 64, M_ / 64), 256, 0, stream>>>(
        xclean, IN_, in_w, IN_, h, H_, IN_, in_b, mask, 0);

    for (int l = 0; l < L_; ++l) {
        const float* ipw = in_proj_w + (size_t)l * 2 * Di_ * H_;
        const float* cwl = conv_w    + (size_t)l * Di_ * KC_;
        const float* cbl = conv_b    + (size_t)l * Di_;
        const float* xpw = x_proj_w  + (size_t)l * 64 * Di_;
        const float* dpw = dt_proj_w + (size_t)l * Di_ * R_;
        const float* dpb = dt_proj_b + (size_t)l * Di_;
        const float* Al  = A_log     + (size_t)l * Di_ * S_;
        const float* Dpl = D_ssm     + (size_t)l * Di_;
        const float* oww = mb_out_w  + (size_t)l * H_ * Di_;
        const float* rwl = rms_w     + (size_t)l * H_;

        // xn = rms(h) * rms_w
        rms_norm_kernel<<<M_, 256, 0, stream>>>(h, rwl, xn);

        // xz = xn @ ipw.T   (M, 2Di)
        gemm_nt<false><<<dim3(2 * Di_ / 64, M_ / 64), 256, 0, stream>>>(
            xn, H_, ipw, H_, xz, 2 * Di_, H_, nullptr, nullptr, 0);

        // u = silu(causal depthwise conv(xz[:, :Di]))
        conv_silu_kernel<<<(M_ * Di_) / 256, 256, 0, stream>>>(xz, cwl, cbl, u);

        // xd = u @ xpw.T   (M, 64)
        gemm_nt<false><<<dim3(64 / 64, M_ / 64), 256, 0, stream>>>(
            u, Di_, xpw, Di_, xd, 64, Di_, nullptr, nullptr, 0);

        // delta = softplus(xd[:, :32] @ dpw.T + dpb)   (M, Di)
        gemm_nt<false><<<dim3(Di_ / 64, M_ / 64), 256, 0, stream>>>(
            xd, 64, dpw, R_, delta, Di_, R_, dpb, nullptr, 1);

        // selective scan -> y (in-place over u), includes +u*D and *silu(z)
        scan_kernel<<<B_ * (Di_ / 256), 256, 0, stream>>>(
            delta, u, xd, xz, Al, Dpl, u);

        // h += y @ oww.T
        gemm_nt<true><<<dim3(H_ / 64, M_ / 64), 256, 0, stream>>>(
            u, Di_, oww, Di_, h, H_, Di_, nullptr, nullptr, 0);
    }

    // LayerNorm -> xn (reused)
    layer_norm_kernel<<<M_, 256, 0, stream>>>(h, ln_g, ln_b, xn);

    // out = xn @ out_w.T + out_b
    gemm_nt<false><<<dim3(OUT_ / 64, M_ / 64), 256, 0, stream>>>(
        xn, H_, out_w, H_, (float*)d_out, OUT_, H_, out_b, nullptr, 0);
}

// Round 2
// 1532.195 us; speedup vs baseline: 4.0275x; 4.0275x over previous
//
#include <hip/hip_runtime.h>
#include <hip/hip_bf16.h>
#include <math.h>

// Problem constants
#define B_  4
#define T_  1024
#define IN_ 256
#define H_  512
#define L_  4
#define Di_ 1024
#define S_  16
#define R_  32
#define KC_ 4
#define OUT_ 256
#define M_  (B_*T_)          // 4096 rows everywhere

#define RMS_EPS 1.1920929e-07f
#define LN_EPS  1e-05f

// ---------------------------------------------------------------------------
// prep: nan_to_num + per-row nan mask (x: (M, IN_)), block = 256 = IN_
// ---------------------------------------------------------------------------
__global__ __launch_bounds__(256) void prep_kernel(const float* __restrict__ x,
                                                   float* __restrict__ xclean,
                                                   float* __restrict__ mask) {
    int row = blockIdx.x;
    int tid = threadIdx.x;
    float v = x[(size_t)row * IN_ + tid];
    int isn = isnan(v) ? 1 : 0;
    xclean[(size_t)row * IN_ + tid] = isn ? 0.f : v;
    __shared__ int f;
    if (tid == 0) f = 0;
    __syncthreads();
    if (isn) f = 1;
    __syncthreads();
    if (tid == 0) mask[row] = f ? 0.f : 1.f;
}

// ---------------------------------------------------------------------------
// Generic f32 GEMM:  C[m,n] (+)= act( A[m,:k] . W[n,:k] + bias[n] ) * rowmask[m]
// 64x64 tile, BK=16, 256 threads, 4x4 micro-tile. M,N % 64 == 0, K % 16 == 0.
// act: 0 = none, 1 = softplus
// ---------------------------------------------------------------------------
#define LDSP 68   // padded LDS row stride (floats)
template<bool ACC>
__global__ __launch_bounds__(256) void gemm_nt(const float* __restrict__ A, int lda,
                                               const float* __restrict__ W, int ldw,
                                               float* __restrict__ C, int ldc,
                                               int K,
                                               const float* __restrict__ bias,
                                               const float* __restrict__ rowmask,
                                               int act) {
    __shared__ float As[16 * LDSP];
    __shared__ float Ws[16 * LDSP];
    const int bm = blockIdx.y * 64;
    const int bn = blockIdx.x * 64;
    const int tid = threadIdx.x;
    const int ty = tid >> 4;
    const int tx = tid & 15;

    float acc[4][4] = {};

    for (int k0 = 0; k0 < K; k0 += 16) {
        #pragma unroll
        for (int i = 0; i < 4; ++i) {
            int idx = tid + i * 256;
            int r = idx >> 4, kk = idx & 15;
            As[kk * LDSP + r] = A[(size_t)(bm + r) * lda + k0 + kk];
            Ws[kk * LDSP + r] = W[(size_t)(bn + r) * ldw + k0 + kk];
        }
        __syncthreads();
        #pragma unroll
        for (int kk = 0; kk < 16; ++kk) {
            float4 av = *reinterpret_cast<const float4*>(&As[kk * LDSP + ty * 4]);
            float4 bv = *reinterpret_cast<const float4*>(&Ws[kk * LDSP + tx * 4]);
            float a[4] = {av.x, av.y, av.z, av.w};
            float b[4] = {bv.x, bv.y, bv.z, bv.w};
            #pragma unroll
            for (int i = 0; i < 4; ++i)
                #pragma unroll
                for (int j = 0; j < 4; ++j)
                    acc[i][j] = fmaf(a[i], b[j], acc[i][j]);
        }
        __syncthreads();
    }

    #pragma unroll
    for (int i = 0; i < 4; ++i) {
        int m = bm + ty * 4 + i;
        float rm = rowmask ? rowmask[m] : 1.f;
        #pragma unroll
        for (int j = 0; j < 4; ++j) {
            int n = bn + tx * 4 + j;
            float v = acc[i][j];
            if (bias) v += bias[n];
            if (act == 1) v = (v > 20.f) ? v : log1pf(__expf(v));
            v *= rm;
            float* p = &C[(size_t)m * ldc + n];
            if (ACC) v += *p;
            *p = v;
        }
    }
}

// ---------------------------------------------------------------------------
// RMSNorm over last dim H_=512. One block (256 thr) per row.
// ---------------------------------------------------------------------------
__global__ __launch_bounds__(256) void rms_norm_kernel(const float* __restrict__ h,
                                                       const float* __restrict__ w,
                                                       float* __restrict__ xn) {
    int row = blockIdx.x, tid = threadIdx.x;
    const float* hr = h + (size_t)row * H_;
    float v0 = hr[tid], v1 = hr[tid + 256];
    float s = v0 * v0 + v1 * v1;
    #pragma unroll
    for (int off = 32; off > 0; off >>= 1) s += __shfl_down(s, off);
    __shared__ float red[4];
    int wid = tid >> 6, lane = tid & 63;
    if (lane == 0) red[wid] = s;
    __syncthreads();
    float tot = red[0] + red[1] + red[2] + red[3];
    float sc = rsqrtf(tot * (1.f / H_) + RMS_EPS);
    xn[(size_t)row * H_ + tid]       = v0 * sc * w[tid];
    xn[(size_t)row * H_ + tid + 256] = v1 * sc * w[tid + 256];
}

// ---------------------------------------------------------------------------
// LayerNorm over last dim H_=512 (two-pass). One block per row.
// ---------------------------------------------------------------------------
__global__ __launch_bounds__(256) void layer_norm_kernel(const float* __restrict__ h,
                                                         const float* __restrict__ g,
                                                         const float* __restrict__ bb,
                                                         float* __restrict__ out) {
    int row = blockIdx.x, tid = threadIdx.x;
    const float* hr = h + (size_t)row * H_;
    float v0 = hr[tid], v1 = hr[tid + 256];
    float s = v0 + v1;
    #pragma unroll
    for (int off = 32; off > 0; off >>= 1) s += __shfl_down(s, off);
    __shared__ float red[4];
    int wid = tid >> 6, lane = tid & 63;
    if (lane == 0) red[wid] = s;
    __syncthreads();
    float mu = (red[0] + red[1] + red[2] + red[3]) * (1.f / H_);
    __syncthreads();
    float d0 = v0 - mu, d1 = v1 - mu;
    float q = d0 * d0 + d1 * d1;
    #pragma unroll
    for (int off = 32; off > 0; off >>= 1) q += __shfl_down(q, off);
    if (lane == 0) red[wid] = q;
    __syncthreads();
    float var = (red[0] + red[1] + red[2] + red[3]) * (1.f / H_);
    float sc = rsqrtf(var + LN_EPS);
    out[(size_t)row * H_ + tid]       = d0 * sc * g[tid]       + bb[tid];
    out[(size_t)row * H_ + tid + 256] = d1 * sc * g[tid + 256] + bb[tid + 256];
}

// ---------------------------------------------------------------------------
// Causal depthwise conv (K=4, left-pad 3) + SiLU.
// ---------------------------------------------------------------------------
__global__ __launch_bounds__(256) void conv_silu_kernel(const float* __restrict__ xz,
                                                        const float* __restrict__ cw,
                                                        const float* __restrict__ cb,
                                                        float* __restrict__ u) {
    int idx = blockIdx.x * 256 + threadIdx.x;
    int c  = idx & (Di_ - 1);
    int bt = idx >> 10;
    int t  = bt & (T_ - 1);
    const float* base = xz + (size_t)bt * (2 * Di_) + c;
    float w0 = cw[c * KC_ + 0], w1 = cw[c * KC_ + 1];
    float w2 = cw[c * KC_ + 2], w3 = cw[c * KC_ + 3];
    float acc = cb[c];
    acc += base[0] * w3;
    if (t >= 1) acc += base[-(1 * 2 * Di_)] * w2;
    if (t >= 2) acc += base[-(2 * 2 * Di_)] * w1;
    if (t >= 3) acc += base[-(3 * 2 * Di_)] * w0;
    u[idx] = acc * (1.f / (1.f + __expf(-acc)));
}

// ---------------------------------------------------------------------------
// Chunked selective scan.
// Recurrence per (b, c, s):  h_t = h_{t-1} * exp(d_t*A_s) + d_t*u_t*B_t[s]
// pass1: per chunk, local end-state E[s] (h0=0) and decay P[s]=exp(A_s*sum d)
// pass2: sequential carry combine over chunks (in-place: hend -> H_in)
// pass3: rerun chunk from H_in, emit y = sum_s h*C + u*D, gated by silu(z)
// Buffers aprod/hend: [b][chunk][s][c] for coalesced c-fastest access.
// ---------------------------------------------------------------------------
__global__ __launch_bounds__(256) void scan_pass1(const float* __restrict__ delta,
                                                  const float* __restrict__ u_in,
                                                  const float* __restrict__ xd,
                                                  const float* __restrict__ A_log,
                                                  float* __restrict__ aprod,
                                                  float* __restrict__ hend,
                                                  int NC, int CL) {
    __shared__ float bc[128 * 32];           // sized for max CL=128
    int blk = blockIdx.x;
    int g = blk & 3;                         // channel group (Di/256 = 4)
    int bk = blk >> 2;                       // b*NC + k
    int k = bk % NC, b = bk / NC;
    int tid = threadIdx.x;
    int c = (g << 8) + tid;
    size_t bt0 = (size_t)b * T_ + (size_t)k * CL;

    for (int i = tid; i < CL * 32; i += 256) {
        int tt = i >> 5, j = i & 31;
        bc[i] = xd[(bt0 + tt) * 64 + 32 + j];
    }
    __syncthreads();

    float Ac[S_];
    #pragma unroll
    for (int s = 0; s < S_; ++s) Ac[s] = -__expf(A_log[c * S_ + s]);

    float h[S_] = {};
    float dsum = 0.f;
    for (int tt = 0; tt < CL; ++tt) {
        size_t bt = bt0 + tt;
        float d  = delta[bt * Di_ + c];
        float uu = u_in[bt * Di_ + c];
        float du = d * uu;
        dsum += d;
        #pragma unroll
        for (int s = 0; s < S_; ++s)
            h[s] = h[s] * __expf(d * Ac[s]) + du * bc[tt * 32 + s];
    }
    size_t pbase = ((size_t)(b * NC + k) * S_) * Di_ + c;
    #pragma unroll
    for (int s = 0; s < S_; ++s) {
        aprod[pbase + (size_t)s * Di_] = __expf(dsum * Ac[s]);
        hend [pbase + (size_t)s * Di_] = h[s];
    }
}

__global__ __launch_bounds__(256) void scan_pass2(const float* __restrict__ aprod,
                                                  float* __restrict__ hend,
                                                  int NC) {
    int gid = blockIdx.x * 256 + threadIdx.x;  // B*S*Di = 65536
    int c = gid & (Di_ - 1);
    int s = (gid >> 10) & (S_ - 1);
    int b = gid >> 14;
    float H = 0.f;
    for (int k = 0; k < NC; ++k) {
        size_t idx = ((size_t)(b * NC + k) * S_ + s) * Di_ + c;
        float pk = aprod[idx];
        float ek = hend[idx];
        hend[idx] = H;               // becomes H_in for chunk k
        H = ek + pk * H;
    }
}

__global__ __launch_bounds__(256) void scan_pass3(const float* __restrict__ delta,
                                                  const float* u_in,
                                                  const float* __restrict__ xd,
                                                  const float* __restrict__ xz,
                                                  const float* __restrict__ A_log,
                                                  const float* __restrict__ D_ssm,
                                                  const float* __restrict__ hend,
                                                  float* y_out,
                                                  int NC, int CL) {
    __shared__ float bc[128 * 32];
    int blk = blockIdx.x;
    int g = blk & 3;
    int bk = blk >> 2;
    int k = bk % NC, b = bk / NC;
    int tid = threadIdx.x;
    int c = (g << 8) + tid;
    size_t bt0 = (size_t)b * T_ + (size_t)k * CL;

    for (int i = tid; i < CL * 32; i += 256) {
        int tt = i >> 5, j = i & 31;
        bc[i] = xd[(bt0 + tt) * 64 + 32 + j];
    }
    __syncthreads();

    float Ac[S_];
    #pragma unroll
    for (int s = 0; s < S_; ++s) Ac[s] = -__expf(A_log[c * S_ + s]);
    float Dp = D_ssm[c];

    float h[S_];
    size_t pbase = ((size_t)(b * NC + k) * S_) * Di_ + c;
    #pragma unroll
    for (int s = 0; s < S_; ++s) h[s] = hend[pbase + (size_t)s * Di_];

    for (int tt = 0; tt < CL; ++tt) {
        size_t bt = bt0 + tt;
        float d  = delta[bt * Di_ + c];
        float uu = u_in[bt * Di_ + c];
        float du = d * uu;
        float y = 0.f;
        #pragma unroll
        for (int s = 0; s < S_; ++s) {
            h[s] = h[s] * __expf(d * Ac[s]) + du * bc[tt * 32 + s];
            y = fmaf(h[s], bc[tt * 32 + 16 + s], y);
        }
        y += uu * Dp;
        float zz = xz[bt * (2 * Di_) + Di_ + c];
        float sig = 1.f / (1.f + __expf(-zz));
        y_out[bt * Di_ + c] = y * (zz * sig);
    }
}

// ---------------------------------------------------------------------------
// Host launch
// ---------------------------------------------------------------------------
extern "C" void kernel_launch(void* const* d_in, const int* in_sizes, int n_in,
                              void* d_out, int out_size, void* d_ws, size_t ws_size,
                              hipStream_t stream) {
    const float* x         = (const float*)d_in[0];
    const float* in_w      = (const float*)d_in[1];
    const float* in_b      = (const float*)d_in[2];
    const float* rms_w     = (const float*)d_in[3];
    const float* in_proj_w = (const float*)d_in[4];
    const float* conv_w    = (const float*)d_in[5];
    const float* conv_b    = (const float*)d_in[6];
    const float* x_proj_w  = (const float*)d_in[7];
    const float* dt_proj_w = (const float*)d_in[8];
    const float* dt_proj_b = (const float*)d_in[9];
    const float* A_log     = (const float*)d_in[10];
    const float* D_ssm     = (const float*)d_in[11];
    const float* mb_out_w  = (const float*)d_in[12];
    const float* ln_g      = (const float*)d_in[13];
    const float* ln_b      = (const float*)d_in[14];
    const float* out_w     = (const float*)d_in[15];
    const float* out_b     = (const float*)d_in[16];

    float* ws = (float*)d_ws;
    float* h      = ws;
    float* xn     = h      + (size_t)M_ * H_;
    float* xz     = xn     + (size_t)M_ * H_;
    float* u      = xz     + (size_t)M_ * 2 * Di_;
    float* xd     = u      + (size_t)M_ * Di_;
    float* delta  = xd     + (size_t)M_ * 64;
    float* xclean = delta;                       // alias (M*IN <= M*Di)
    float* mask   = delta  + (size_t)M_ * Di_;
    float* aprod  = mask   + M_;
    (void)n_in; (void)in_sizes; (void)out_size;

    // choose chunk count to fit ws: need 2 * B*NC*S*Di floats for aprod/hend
    size_t used = (size_t)(aprod - ws);
    size_t avail = ws_size / 4 > used ? ws_size / 4 - used : 0;
    int NC = 64;
    while (NC > 8 && 2 * (size_t)B_ * NC * S_ * Di_ > avail) NC >>= 1;
    int CL = T_ / NC;
    float* hend = aprod + (size_t)B_ * NC * S_ * Di_;

    // 1) nan handling
    prep_kernel<<<M_, 256, 0, stream>>>(x, xclean, mask);

    // 2) h = (xclean @ in_w.T + in_b) * mask
    gemm_nt<false><<<dim3(H_ / 64, M_ / 64), 256, 0, stream>>>(
        xclean, IN_, in_w, IN_, h, H_, IN_, in_b, mask, 0);

    for (int l = 0; l < L_; ++l) {
        const float* ipw = in_proj_w + (size_t)l * 2 * Di_ * H_;
        const float* cwl = conv_w    + (size_t)l * Di_ * KC_;
        const float* cbl = conv_b    + (size_t)l * Di_;
        const float* xpw = x_proj_w  + (size_t)l * 64 * Di_;
        const float* dpw = dt_proj_w + (size_t)l * Di_ * R_;
        const float* dpb = dt_proj_b + (size_t)l * Di_;
        const float* Al  = A_log     + (size_t)l * Di_ * S_;
        const float* Dpl = D_ssm     + (size_t)l * Di_;
        const float* oww = mb_out_w  + (size_t)l * H_ * Di_;
        const float* rwl = rms_w     + (size_t)l * H_;

        rms_norm_kernel<<<M_, 256, 0, stream>>>(h, rwl, xn);

        gemm_nt<false><<<dim3(2 * Di_ / 64, M_ / 64), 256, 0, stream>>>(
            xn, H_, ipw, H_, xz, 2 * Di_, H_, nullptr, nullptr, 0);

        conv_silu_kernel<<<(M_ * Di_) / 256, 256, 0, stream>>>(xz, cwl, cbl, u);

        gemm_nt<false><<<dim3(64 / 64, M_ / 64), 256, 0, stream>>>(
            u, Di_, xpw, Di_, xd, 64, Di_, nullptr, nullptr, 0);

        gemm_nt<false><<<dim3(Di_ / 64, M_ / 64), 256, 0, stream>>>(
            xd, 64, dpw, R_, delta, Di_, R_, dpb, nullptr, 1);

        // chunked scan
        scan_pass1<<<B_ * NC * (Di_ / 256), 256, 0, stream>>>(
            delta, u, xd, Al, aprod, hend, NC, CL);
        scan_pass2<<<(B_ * S_ * Di_) / 256, 256, 0, stream>>>(aprod, hend, NC);
        scan_pass3<<<B_ * NC * (Di_ / 256), 256, 0, stream>>>(
            delta, u, xd, xz, Al, Dpl, hend, u, NC, CL);

        gemm_nt<true><<<dim3(H_ / 64, M_ / 64), 256, 0, stream>>>(
            u, Di_, oww, Di_, h, H_, Di_, nullptr, nullptr, 0);
    }

    layer_norm_kernel<<<M_, 256, 0, stream>>>(h, ln_g, ln_b, xn);

    gemm_nt<false><<<dim3(OUT_ / 64, M_ / 64), 256, 0, stream>>>(
        xn, H_, out_w, H_, (float*)d_out, OUT_, H_, out_b, nullptr, 0);
}

// Round 3
// 988.005 us; speedup vs baseline: 6.2458x; 1.5508x over previous
//
#include <hip/hip_runtime.h>
#include <hip/hip_bf16.h>
#include <math.h>

// Problem constants
#define B_  4
#define T_  1024
#define IN_ 256
#define H_  512
#define L_  4
#define Di_ 1024
#define S_  16
#define R_  32
#define KC_ 4
#define OUT_ 256
#define M_  (B_*T_)          // 4096 rows everywhere

#define RMS_EPS 1.1920929e-07f
#define LN_EPS  1e-05f

typedef __attribute__((ext_vector_type(8))) short  s16x8;   // 8 bf16
typedef __attribute__((ext_vector_type(4))) float  f32x4;
typedef __hip_bfloat16 bf16_t;

// ---------------------------------------------------------------------------
// f32 -> bf16 conversion (weights), 4 elems/thread
// ---------------------------------------------------------------------------
__global__ __launch_bounds__(256) void cvt_f32_bf16(const float* __restrict__ s,
                                                    bf16_t* __restrict__ d, int n) {
    int i = (blockIdx.x * 256 + threadIdx.x) * 4;
    if (i >= n) return;
    float4 v = *reinterpret_cast<const float4*>(s + i);
    d[i + 0] = __float2bfloat16(v.x);
    d[i + 1] = __float2bfloat16(v.y);
    d[i + 2] = __float2bfloat16(v.z);
    d[i + 3] = __float2bfloat16(v.w);
}

// ---------------------------------------------------------------------------
// prep: nan_to_num + per-row nan mask; writes bf16 xclean
// ---------------------------------------------------------------------------
__global__ __launch_bounds__(256) void prep_kernel(const float* __restrict__ x,
                                                   bf16_t* __restrict__ xclbf,
                                                   float* __restrict__ mask) {
    int row = blockIdx.x;
    int tid = threadIdx.x;
    float v = x[(size_t)row * IN_ + tid];
    int isn = isnan(v) ? 1 : 0;
    xclbf[(size_t)row * IN_ + tid] = __float2bfloat16(isn ? 0.f : v);
    __shared__ int f;
    if (tid == 0) f = 0;
    __syncthreads();
    if (isn) f = 1;
    __syncthreads();
    if (tid == 0) mask[row] = f ? 0.f : 1.f;
}

// ---------------------------------------------------------------------------
// bf16 MFMA GEMM: C[m,n] (+)= (A[m,:] . W[n,:] + bias[n]) * rowmask[m]
// A:(M,K) bf16, W:(N,K) bf16, C f32. 128x128 tile, BK=64, 256 thr = 4 waves,
// each wave 64x64 (4x4 frags of 16x16x32 MFMA).
// LDS layout: fragment-contiguous [k-chunk(8)][row(128)][8 bf16] per operand.
// M,N % 128 == 0, K % 64 == 0.
// ---------------------------------------------------------------------------
template<bool ACC>
__global__ __launch_bounds__(256) void gemm_bf16(const bf16_t* __restrict__ A, int lda,
                                                 const bf16_t* __restrict__ W, int ldw,
                                                 float* __restrict__ C, int ldc,
                                                 int K,
                                                 const float* __restrict__ bias,
                                                 const float* __restrict__ rowmask) {
    __shared__ s16x8 As[1024];   // 16 KB: [chunk][row]
    __shared__ s16x8 Ws[1024];   // 16 KB
    const int bm = blockIdx.y * 128;
    const int bn = blockIdx.x * 128;
    const int tid  = threadIdx.x;
    const int lane = tid & 63;
    const int w    = tid >> 6;
    const int wr   = w >> 1;     // wave row (0..1)
    const int wc   = w & 1;      // wave col (0..1)

    f32x4 acc[4][4] = {};

    for (int k0 = 0; k0 < K; k0 += 64) {
        #pragma unroll
        for (int i = 0; i < 4; ++i) {
            int gbase = i * 256 + w * 64;       // wave-uniform LDS block base
            int g = gbase + lane;
            int chunk = g >> 7, row = g & 127;
            const bf16_t* sA = A + (size_t)(bm + row) * lda + (k0 + chunk * 8);
            const bf16_t* sW = W + (size_t)(bn + row) * ldw + (k0 + chunk * 8);
            __builtin_amdgcn_global_load_lds(
                (const __attribute__((address_space(1))) void*)sA,
                (__attribute__((address_space(3))) void*)((char*)As + gbase * 16),
                16, 0, 0);
            __builtin_amdgcn_global_load_lds(
                (const __attribute__((address_space(1))) void*)sW,
                (__attribute__((address_space(3))) void*)((char*)Ws + gbase * 16),
                16, 0, 0);
        }
        __syncthreads();

        #pragma unroll
        for (int ks = 0; ks < 2; ++ks) {
            const int cbase = (ks * 4 + (lane >> 4)) * 128;
            const int arow = wr * 64 + (lane & 15);
            const int brow = wc * 64 + (lane & 15);
            s16x8 af[4], bfr[4];
            #pragma unroll
            for (int f = 0; f < 4; ++f) {
                af[f]  = As[cbase + arow + f * 16];
                bfr[f] = Ws[cbase + brow + f * 16];
            }
            #pragma unroll
            for (int mf = 0; mf < 4; ++mf)
                #pragma unroll
                for (int nf = 0; nf < 4; ++nf)
                    acc[mf][nf] = __builtin_amdgcn_mfma_f32_16x16x32_bf16(
                        af[mf], bfr[nf], acc[mf][nf], 0, 0, 0);
        }
        __syncthreads();
    }

    // epilogue: C/D frag layout col=lane&15, row=(lane>>4)*4+reg
    #pragma unroll
    for (int mf = 0; mf < 4; ++mf) {
        int rbase = bm + wr * 64 + mf * 16 + ((lane >> 4) << 2);
        #pragma unroll
        for (int nf = 0; nf < 4; ++nf) {
            int n = bn + wc * 64 + nf * 16 + (lane & 15);
            float bv = bias ? bias[n] : 0.f;
            #pragma unroll
            for (int r = 0; r < 4; ++r) {
                int m = rbase + r;
                float v = acc[mf][nf][r] + bv;
                if (rowmask) v *= rowmask[m];
                float* p = &C[(size_t)m * ldc + n];
                if (ACC) v += *p;
                *p = v;
            }
        }
    }
}

// ---------------------------------------------------------------------------
// Generic f32 GEMM (kept for x_proj / dt_proj small shapes).
// 64x64 tile, BK=16, 256 threads, 4x4 micro-tile. act: 0=none, 1=softplus
// ---------------------------------------------------------------------------
#define LDSP 68
__global__ __launch_bounds__(256) void gemm_nt(const float* __restrict__ A, int lda,
                                               const float* __restrict__ W, int ldw,
                                               float* __restrict__ C, int ldc,
                                               int K,
                                               const float* __restrict__ bias,
                                               int act) {
    __shared__ float As[16 * LDSP];
    __shared__ float Ws[16 * LDSP];
    const int bm = blockIdx.y * 64;
    const int bn = blockIdx.x * 64;
    const int tid = threadIdx.x;
    const int ty = tid >> 4;
    const int tx = tid & 15;

    float acc[4][4] = {};

    for (int k0 = 0; k0 < K; k0 += 16) {
        #pragma unroll
        for (int i = 0; i < 4; ++i) {
            int idx = tid + i * 256;
            int r = idx >> 4, kk = idx & 15;
            As[kk * LDSP + r] = A[(size_t)(bm + r) * lda + k0 + kk];
            Ws[kk * LDSP + r] = W[(size_t)(bn + r) * ldw + k0 + kk];
        }
        __syncthreads();
        #pragma unroll
        for (int kk = 0; kk < 16; ++kk) {
            float4 av = *reinterpret_cast<const float4*>(&As[kk * LDSP + ty * 4]);
            float4 bv = *reinterpret_cast<const float4*>(&Ws[kk * LDSP + tx * 4]);
            float a[4] = {av.x, av.y, av.z, av.w};
            float b[4] = {bv.x, bv.y, bv.z, bv.w};
            #pragma unroll
            for (int i = 0; i < 4; ++i)
                #pragma unroll
                for (int j = 0; j < 4; ++j)
                    acc[i][j] = fmaf(a[i], b[j], acc[i][j]);
        }
        __syncthreads();
    }

    #pragma unroll
    for (int i = 0; i < 4; ++i) {
        int m = bm + ty * 4 + i;
        #pragma unroll
        for (int j = 0; j < 4; ++j) {
            int n = bn + tx * 4 + j;
            float v = acc[i][j];
            if (bias) v += bias[n];
            if (act == 1) v = (v > 20.f) ? v : log1pf(__expf(v));
            C[(size_t)m * ldc + n] = v;
        }
    }
}

// ---------------------------------------------------------------------------
// RMSNorm over last dim H_=512; writes bf16. One block (256 thr) per row.
// ---------------------------------------------------------------------------
__global__ __launch_bounds__(256) void rms_norm_kernel(const float* __restrict__ h,
                                                       const float* __restrict__ w,
                                                       bf16_t* __restrict__ xnbf) {
    int row = blockIdx.x, tid = threadIdx.x;
    const float* hr = h + (size_t)row * H_;
    float v0 = hr[tid], v1 = hr[tid + 256];
    float s = v0 * v0 + v1 * v1;
    #pragma unroll
    for (int off = 32; off > 0; off >>= 1) s += __shfl_down(s, off);
    __shared__ float red[4];
    int wid = tid >> 6, lane = tid & 63;
    if (lane == 0) red[wid] = s;
    __syncthreads();
    float tot = red[0] + red[1] + red[2] + red[3];
    float sc = rsqrtf(tot * (1.f / H_) + RMS_EPS);
    xnbf[(size_t)row * H_ + tid]       = __float2bfloat16(v0 * sc * w[tid]);
    xnbf[(size_t)row * H_ + tid + 256] = __float2bfloat16(v1 * sc * w[tid + 256]);
}

// ---------------------------------------------------------------------------
// LayerNorm over last dim H_=512; writes bf16. One block per row.
// ---------------------------------------------------------------------------
__global__ __launch_bounds__(256) void layer_norm_kernel(const float* __restrict__ h,
                                                         const float* __restrict__ g,
                                                         const float* __restrict__ bb,
                                                         bf16_t* __restrict__ out) {
    int row = blockIdx.x, tid = threadIdx.x;
    const float* hr = h + (size_t)row * H_;
    float v0 = hr[tid], v1 = hr[tid + 256];
    float s = v0 + v1;
    #pragma unroll
    for (int off = 32; off > 0; off >>= 1) s += __shfl_down(s, off);
    __shared__ float red[4];
    int wid = tid >> 6, lane = tid & 63;
    if (lane == 0) red[wid] = s;
    __syncthreads();
    float mu = (red[0] + red[1] + red[2] + red[3]) * (1.f / H_);
    __syncthreads();
    float d0 = v0 - mu, d1 = v1 - mu;
    float q = d0 * d0 + d1 * d1;
    #pragma unroll
    for (int off = 32; off > 0; off >>= 1) q += __shfl_down(q, off);
    if (lane == 0) red[wid] = q;
    __syncthreads();
    float var = (red[0] + red[1] + red[2] + red[3]) * (1.f / H_);
    float sc = rsqrtf(var + LN_EPS);
    out[(size_t)row * H_ + tid]       = __float2bfloat16(d0 * sc * g[tid]       + bb[tid]);
    out[(size_t)row * H_ + tid + 256] = __float2bfloat16(d1 * sc * g[tid + 256] + bb[tid + 256]);
}

// ---------------------------------------------------------------------------
// Causal depthwise conv (K=4, left-pad 3) + SiLU.
// ---------------------------------------------------------------------------
__global__ __launch_bounds__(256) void conv_silu_kernel(const float* __restrict__ xz,
                                                        const float* __restrict__ cw,
                                                        const float* __restrict__ cb,
                                                        float* __restrict__ u) {
    int idx = blockIdx.x * 256 + threadIdx.x;
    int c  = idx & (Di_ - 1);
    int bt = idx >> 10;
    int t  = bt & (T_ - 1);
    const float* base = xz + (size_t)bt * (2 * Di_) + c;
    float w0 = cw[c * KC_ + 0], w1 = cw[c * KC_ + 1];
    float w2 = cw[c * KC_ + 2], w3 = cw[c * KC_ + 3];
    float acc = cb[c];
    acc += base[0] * w3;
    if (t >= 1) acc += base[-(1 * 2 * Di_)] * w2;
    if (t >= 2) acc += base[-(2 * 2 * Di_)] * w1;
    if (t >= 3) acc += base[-(3 * 2 * Di_)] * w0;
    u[idx] = acc * (1.f / (1.f + __expf(-acc)));
}

// ---------------------------------------------------------------------------
// Chunked selective scan (3 passes). pass3 writes bf16 y (gated).
// ---------------------------------------------------------------------------
__global__ __launch_bounds__(256) void scan_pass1(const float* __restrict__ delta,
                                                  const float* __restrict__ u_in,
                                                  const float* __restrict__ xd,
                                                  const float* __restrict__ A_log,
                                                  float* __restrict__ aprod,
                                                  float* __restrict__ hend,
                                                  int NC, int CL) {
    __shared__ float bc[128 * 32];
    int blk = blockIdx.x;
    int g = blk & 3;
    int bk = blk >> 2;
    int k = bk % NC, b = bk / NC;
    int tid = threadIdx.x;
    int c = (g << 8) + tid;
    size_t bt0 = (size_t)b * T_ + (size_t)k * CL;

    for (int i = tid; i < CL * 32; i += 256) {
        int tt = i >> 5, j = i & 31;
        bc[i] = xd[(bt0 + tt) * 64 + 32 + j];
    }
    __syncthreads();

    float Ac[S_];
    #pragma unroll
    for (int s = 0; s < S_; ++s) Ac[s] = -__expf(A_log[c * S_ + s]);

    float h[S_] = {};
    float dsum = 0.f;
    for (int tt = 0; tt < CL; ++tt) {
        size_t bt = bt0 + tt;
        float d  = delta[bt * Di_ + c];
        float uu = u_in[bt * Di_ + c];
        float du = d * uu;
        dsum += d;
        #pragma unroll
        for (int s = 0; s < S_; ++s)
            h[s] = h[s] * __expf(d * Ac[s]) + du * bc[tt * 32 + s];
    }
    size_t pbase = ((size_t)(b * NC + k) * S_) * Di_ + c;
    #pragma unroll
    for (int s = 0; s < S_; ++s) {
        aprod[pbase + (size_t)s * Di_] = __expf(dsum * Ac[s]);
        hend [pbase + (size_t)s * Di_] = h[s];
    }
}

__global__ __launch_bounds__(256) void scan_pass2(const float* __restrict__ aprod,
                                                  float* __restrict__ hend,
                                                  int NC) {
    int gid = blockIdx.x * 256 + threadIdx.x;  // B*S*Di
    int c = gid & (Di_ - 1);
    int s = (gid >> 10) & (S_ - 1);
    int b = gid >> 14;
    float H = 0.f;
    for (int k = 0; k < NC; ++k) {
        size_t idx = ((size_t)(b * NC + k) * S_ + s) * Di_ + c;
        float pk = aprod[idx];
        float ek = hend[idx];
        hend[idx] = H;
        H = ek + pk * H;
    }
}

__global__ __launch_bounds__(256) void scan_pass3(const float* __restrict__ delta,
                                                  const float* __restrict__ u_in,
                                                  const float* __restrict__ xd,
                                                  const float* __restrict__ xz,
                                                  const float* __restrict__ A_log,
                                                  const float* __restrict__ D_ssm,
                                                  const float* __restrict__ hend,
                                                  bf16_t* __restrict__ ybf,
                                                  int NC, int CL) {
    __shared__ float bc[128 * 32];
    int blk = blockIdx.x;
    int g = blk & 3;
    int bk = blk >> 2;
    int k = bk % NC, b = bk / NC;
    int tid = threadIdx.x;
    int c = (g << 8) + tid;
    size_t bt0 = (size_t)b * T_ + (size_t)k * CL;

    for (int i = tid; i < CL * 32; i += 256) {
        int tt = i >> 5, j = i & 31;
        bc[i] = xd[(bt0 + tt) * 64 + 32 + j];
    }
    __syncthreads();

    float Ac[S_];
    #pragma unroll
    for (int s = 0; s < S_; ++s) Ac[s] = -__expf(A_log[c * S_ + s]);
    float Dp = D_ssm[c];

    float h[S_];
    size_t pbase = ((size_t)(b * NC + k) * S_) * Di_ + c;
    #pragma unroll
    for (int s = 0; s < S_; ++s) h[s] = hend[pbase + (size_t)s * Di_];

    for (int tt = 0; tt < CL; ++tt) {
        size_t bt = bt0 + tt;
        float d  = delta[bt * Di_ + c];
        float uu = u_in[bt * Di_ + c];
        float du = d * uu;
        float y = 0.f;
        #pragma unroll
        for (int s = 0; s < S_; ++s) {
            h[s] = h[s] * __expf(d * Ac[s]) + du * bc[tt * 32 + s];
            y = fmaf(h[s], bc[tt * 32 + 16 + s], y);
        }
        y += uu * Dp;
        float zz = xz[bt * (2 * Di_) + Di_ + c];
        float sig = 1.f / (1.f + __expf(-zz));
        ybf[bt * Di_ + c] = __float2bfloat16(y * (zz * sig));
    }
}

// ---------------------------------------------------------------------------
// Host launch
// ---------------------------------------------------------------------------
extern "C" void kernel_launch(void* const* d_in, const int* in_sizes, int n_in,
                              void* d_out, int out_size, void* d_ws, size_t ws_size,
                              hipStream_t stream) {
    const float* x         = (const float*)d_in[0];
    const float* in_w      = (const float*)d_in[1];
    const float* in_b      = (const float*)d_in[2];
    const float* rms_w     = (const float*)d_in[3];
    const float* in_proj_w = (const float*)d_in[4];
    const float* conv_w    = (const float*)d_in[5];
    const float* conv_b    = (const float*)d_in[6];
    const float* x_proj_w  = (const float*)d_in[7];
    const float* dt_proj_w = (const float*)d_in[8];
    const float* dt_proj_b = (const float*)d_in[9];
    const float* A_log     = (const float*)d_in[10];
    const float* D_ssm     = (const float*)d_in[11];
    const float* mb_out_w  = (const float*)d_in[12];
    const float* ln_g      = (const float*)d_in[13];
    const float* ln_b      = (const float*)d_in[14];
    const float* out_w     = (const float*)d_in[15];
    const float* out_b     = (const float*)d_in[16];

    float* ws = (float*)d_ws;
    float* h     = ws;
    float* xz    = h     + (size_t)M_ * H_;
    float* u     = xz    + (size_t)M_ * 2 * Di_;
    float* xd    = u     + (size_t)M_ * Di_;
    float* delta = xd    + (size_t)M_ * 64;
    float* mask  = delta + (size_t)M_ * Di_;
    bf16_t* xnbf  = (bf16_t*)(mask + M_);                 // also reused for LN out
    bf16_t* ybf   = xnbf  + (size_t)M_ * H_;
    bf16_t* xclbf = ybf   + (size_t)M_ * Di_;
    bf16_t* inwbf = xclbf + (size_t)M_ * IN_;
    bf16_t* ipwbf = inwbf + (size_t)H_ * IN_;
    bf16_t* owwbf = ipwbf + (size_t)L_ * 2 * Di_ * H_;
    bf16_t* outwbf= owwbf + (size_t)L_ * H_ * Di_;
    float* aprod = (float*)(outwbf + (size_t)OUT_ * H_);
    (void)n_in; (void)in_sizes; (void)out_size;

    size_t used = (size_t)(aprod - ws);
    size_t avail = (ws_size / 4 > used) ? ws_size / 4 - used : 0;
    int NC = 64;
    while (NC > 8 && 2 * (size_t)B_ * NC * S_ * Di_ > avail) NC >>= 1;
    int CL = T_ / NC;
    float* hend = aprod + (size_t)B_ * NC * S_ * Di_;

    // weight conversions (every call: deterministic)
    {
        int n;
        n = H_ * IN_;
        cvt_f32_bf16<<<(n / 4 + 255) / 256, 256, 0, stream>>>(in_w, inwbf, n);
        n = L_ * 2 * Di_ * H_;
        cvt_f32_bf16<<<(n / 4 + 255) / 256, 256, 0, stream>>>(in_proj_w, ipwbf, n);
        n = L_ * H_ * Di_;
        cvt_f32_bf16<<<(n / 4 + 255) / 256, 256, 0, stream>>>(mb_out_w, owwbf, n);
        n = OUT_ * H_;
        cvt_f32_bf16<<<(n / 4 + 255) / 256, 256, 0, stream>>>(out_w, outwbf, n);
    }

    // 1) nan handling
    prep_kernel<<<M_, 256, 0, stream>>>(x, xclbf, mask);

    // 2) h = (xclean @ in_w.T + in_b) * mask   [bf16 MFMA]
    gemm_bf16<false><<<dim3(H_ / 128, M_ / 128), 256, 0, stream>>>(
        xclbf, IN_, inwbf, IN_, h, H_, IN_, in_b, mask);

    for (int l = 0; l < L_; ++l) {
        const bf16_t* ipw = ipwbf + (size_t)l * 2 * Di_ * H_;
        const float* cwl = conv_w    + (size_t)l * Di_ * KC_;
        const float* cbl = conv_b    + (size_t)l * Di_;
        const float* xpw = x_proj_w  + (size_t)l * 64 * Di_;
        const float* dpw = dt_proj_w + (size_t)l * Di_ * R_;
        const float* dpb = dt_proj_b + (size_t)l * Di_;
        const float* Al  = A_log     + (size_t)l * Di_ * S_;
        const float* Dpl = D_ssm     + (size_t)l * Di_;
        const bf16_t* oww = owwbf + (size_t)l * H_ * Di_;
        const float* rwl = rms_w     + (size_t)l * H_;

        rms_norm_kernel<<<M_, 256, 0, stream>>>(h, rwl, xnbf);

        // xz = xn @ ipw.T   [bf16 MFMA]
        gemm_bf16<false><<<dim3(2 * Di_ / 128, M_ / 128), 256, 0, stream>>>(
            xnbf, H_, ipw, H_, xz, 2 * Di_, H_, nullptr, nullptr);

        conv_silu_kernel<<<(M_ * Di_) / 256, 256, 0, stream>>>(xz, cwl, cbl, u);

        // xd = u @ xpw.T  (f32, small N)
        gemm_nt<<<dim3(64 / 64, M_ / 64), 256, 0, stream>>>(
            u, Di_, xpw, Di_, xd, 64, Di_, nullptr, 0);

        // delta = softplus(xd[:, :32] @ dpw.T + dpb)  (f32, K=32)
        gemm_nt<<<dim3(Di_ / 64, M_ / 64), 256, 0, stream>>>(
            xd, 64, dpw, R_, delta, Di_, R_, dpb, 1);

        // chunked scan
        scan_pass1<<<B_ * NC * (Di_ / 256), 256, 0, stream>>>(
            delta, u, xd, Al, aprod, hend, NC, CL);
        scan_pass2<<<(B_ * S_ * Di_) / 256, 256, 0, stream>>>(aprod, hend, NC);
        scan_pass3<<<B_ * NC * (Di_ / 256), 256, 0, stream>>>(
            delta, u, xd, xz, Al, Dpl, hend, ybf, NC, CL);

        // h += y @ oww.T   [bf16 MFMA, ACC]
        gemm_bf16<true><<<dim3(H_ / 128, M_ / 128), 256, 0, stream>>>(
            ybf, Di_, oww, Di_, h, H_, Di_, nullptr, nullptr);
    }

    // LayerNorm -> bf16 (reuse xnbf)
    layer_norm_kernel<<<M_, 256, 0, stream>>>(h, ln_g, ln_b, xnbf);

    // out = hn @ out_w.T + out_b   [bf16 MFMA]
    gemm_bf16<false><<<dim3(OUT_ / 128, M_ / 128), 256, 0, stream>>>(
        xnbf, H_, outwbf, H_, (float*)d_out, OUT_, H_, out_b, nullptr);
}

// Round 4
// 828.382 us; speedup vs baseline: 7.4493x; 1.1927x over previous
//
#include <hip/hip_runtime.h>
#include <hip/hip_bf16.h>
#include <math.h>

// Problem constants
#define B_  4
#define T_  1024
#define IN_ 256
#define H_  512
#define L_  4
#define Di_ 1024
#define S_  16
#define R_  32
#define KC_ 4
#define OUT_ 256
#define M_  (B_*T_)          // 4096 rows everywhere
#define KSPLIT 8             // split-K factor for x_proj

#define RMS_EPS 1.1920929e-07f
#define LN_EPS  1e-05f

typedef __attribute__((ext_vector_type(8))) short  s16x8;   // 8 bf16
typedef __attribute__((ext_vector_type(4))) float  f32x4;
typedef __hip_bfloat16 bf16_t;

// ---------------------------------------------------------------------------
// f32 -> bf16 conversion (weights), 4 elems/thread
// ---------------------------------------------------------------------------
__global__ __launch_bounds__(256) void cvt_f32_bf16(const float* __restrict__ s,
                                                    bf16_t* __restrict__ d, int n) {
    int i = (blockIdx.x * 256 + threadIdx.x) * 4;
    if (i >= n) return;
    float4 v = *reinterpret_cast<const float4*>(s + i);
    d[i + 0] = __float2bfloat16(v.x);
    d[i + 1] = __float2bfloat16(v.y);
    d[i + 2] = __float2bfloat16(v.z);
    d[i + 3] = __float2bfloat16(v.w);
}

// ---------------------------------------------------------------------------
// prep: nan_to_num + per-row nan mask; writes bf16 xclean
// ---------------------------------------------------------------------------
__global__ __launch_bounds__(256) void prep_kernel(const float* __restrict__ x,
                                                   bf16_t* __restrict__ xclbf,
                                                   float* __restrict__ mask) {
    int row = blockIdx.x;
    int tid = threadIdx.x;
    float v = x[(size_t)row * IN_ + tid];
    int isn = isnan(v) ? 1 : 0;
    xclbf[(size_t)row * IN_ + tid] = __float2bfloat16(isn ? 0.f : v);
    __shared__ int f;
    if (tid == 0) f = 0;
    __syncthreads();
    if (isn) f = 1;
    __syncthreads();
    if (tid == 0) mask[row] = f ? 0.f : 1.f;
}

// ---------------------------------------------------------------------------
// bf16 MFMA GEMM: C[m,n] (+)= (A[m,:] . W[n,:] + bias[n]) * rowmask[m]
// 128x128 tile, BK=64, 256 thr = 4 waves, each wave 64x64.
// ---------------------------------------------------------------------------
template<bool ACC>
__global__ __launch_bounds__(256) void gemm_bf16(const bf16_t* __restrict__ A, int lda,
                                                 const bf16_t* __restrict__ W, int ldw,
                                                 float* __restrict__ C, int ldc,
                                                 int K,
                                                 const float* __restrict__ bias,
                                                 const float* __restrict__ rowmask) {
    __shared__ s16x8 As[1024];   // 16 KB: [chunk][row]
    __shared__ s16x8 Ws[1024];   // 16 KB
    const int bm = blockIdx.y * 128;
    const int bn = blockIdx.x * 128;
    const int tid  = threadIdx.x;
    const int lane = tid & 63;
    const int w    = tid >> 6;
    const int wr   = w >> 1;
    const int wc   = w & 1;

    f32x4 acc[4][4] = {};

    for (int k0 = 0; k0 < K; k0 += 64) {
        #pragma unroll
        for (int i = 0; i < 4; ++i) {
            int gbase = i * 256 + w * 64;
            int g = gbase + lane;
            int chunk = g >> 7, row = g & 127;
            const bf16_t* sA = A + (size_t)(bm + row) * lda + (k0 + chunk * 8);
            const bf16_t* sW = W + (size_t)(bn + row) * ldw + (k0 + chunk * 8);
            __builtin_amdgcn_global_load_lds(
                (const __attribute__((address_space(1))) void*)sA,
                (__attribute__((address_space(3))) void*)((char*)As + gbase * 16),
                16, 0, 0);
            __builtin_amdgcn_global_load_lds(
                (const __attribute__((address_space(1))) void*)sW,
                (__attribute__((address_space(3))) void*)((char*)Ws + gbase * 16),
                16, 0, 0);
        }
        __syncthreads();

        #pragma unroll
        for (int ks = 0; ks < 2; ++ks) {
            const int cbase = (ks * 4 + (lane >> 4)) * 128;
            const int arow = wr * 64 + (lane & 15);
            const int brow = wc * 64 + (lane & 15);
            s16x8 af[4], bfr[4];
            #pragma unroll
            for (int f = 0; f < 4; ++f) {
                af[f]  = As[cbase + arow + f * 16];
                bfr[f] = Ws[cbase + brow + f * 16];
            }
            #pragma unroll
            for (int mf = 0; mf < 4; ++mf)
                #pragma unroll
                for (int nf = 0; nf < 4; ++nf)
                    acc[mf][nf] = __builtin_amdgcn_mfma_f32_16x16x32_bf16(
                        af[mf], bfr[nf], acc[mf][nf], 0, 0, 0);
        }
        __syncthreads();
    }

    #pragma unroll
    for (int mf = 0; mf < 4; ++mf) {
        int rbase = bm + wr * 64 + mf * 16 + ((lane >> 4) << 2);
        #pragma unroll
        for (int nf = 0; nf < 4; ++nf) {
            int n = bn + wc * 64 + nf * 16 + (lane & 15);
            float bv = bias ? bias[n] : 0.f;
            #pragma unroll
            for (int r = 0; r < 4; ++r) {
                int m = rbase + r;
                float v = acc[mf][nf][r] + bv;
                if (rowmask) v *= rowmask[m];
                float* p = &C[(size_t)m * ldc + n];
                if (ACC) v += *p;
                *p = v;
            }
        }
    }
}

// ---------------------------------------------------------------------------
// Generic f32 GEMM (dt_proj). 64x64 tile, BK=16. act: 0=none, 1=softplus
// ---------------------------------------------------------------------------
#define LDSP 68
__global__ __launch_bounds__(256) void gemm_nt(const float* __restrict__ A, int lda,
                                               const float* __restrict__ W, int ldw,
                                               float* __restrict__ C, int ldc,
                                               int K,
                                               const float* __restrict__ bias,
                                               int act) {
    __shared__ float As[16 * LDSP];
    __shared__ float Ws[16 * LDSP];
    const int bm = blockIdx.y * 64;
    const int bn = blockIdx.x * 64;
    const int tid = threadIdx.x;
    const int ty = tid >> 4;
    const int tx = tid & 15;

    float acc[4][4] = {};

    for (int k0 = 0; k0 < K; k0 += 16) {
        #pragma unroll
        for (int i = 0; i < 4; ++i) {
            int idx = tid + i * 256;
            int r = idx >> 4, kk = idx & 15;
            As[kk * LDSP + r] = A[(size_t)(bm + r) * lda + k0 + kk];
            Ws[kk * LDSP + r] = W[(size_t)(bn + r) * ldw + k0 + kk];
        }
        __syncthreads();
        #pragma unroll
        for (int kk = 0; kk < 16; ++kk) {
            float4 av = *reinterpret_cast<const float4*>(&As[kk * LDSP + ty * 4]);
            float4 bv = *reinterpret_cast<const float4*>(&Ws[kk * LDSP + tx * 4]);
            float a[4] = {av.x, av.y, av.z, av.w};
            float b[4] = {bv.x, bv.y, bv.z, bv.w};
            #pragma unroll
            for (int i = 0; i < 4; ++i)
                #pragma unroll
                for (int j = 0; j < 4; ++j)
                    acc[i][j] = fmaf(a[i], b[j], acc[i][j]);
        }
        __syncthreads();
    }

    #pragma unroll
    for (int i = 0; i < 4; ++i) {
        int m = bm + ty * 4 + i;
        #pragma unroll
        for (int j = 0; j < 4; ++j) {
            int n = bn + tx * 4 + j;
            float v = acc[i][j];
            if (bias) v += bias[n];
            if (act == 1) v = (v > 20.f) ? v : log1pf(__expf(v));
            C[(size_t)m * ldc + n] = v;
        }
    }
}

// ---------------------------------------------------------------------------
// Split-K f32 GEMM for x_proj: N=64, ldc=64, no bias/act.
// grid (1, M/64, KSPLIT); each z handles Kchunk of K, writes partials.
// ---------------------------------------------------------------------------
__global__ __launch_bounds__(256) void gemm_nt_splitk(const float* __restrict__ A, int lda,
                                                      const float* __restrict__ W, int ldw,
                                                      float* __restrict__ Cpart,
                                                      int Kchunk) {
    __shared__ float As[16 * LDSP];
    __shared__ float Ws[16 * LDSP];
    const int bm = blockIdx.y * 64;
    const int bn = blockIdx.x * 64;
    const int koff = blockIdx.z * Kchunk;
    const int tid = threadIdx.x;
    const int ty = tid >> 4;
    const int tx = tid & 15;

    float acc[4][4] = {};

    for (int k0 = 0; k0 < Kchunk; k0 += 16) {
        #pragma unroll
        for (int i = 0; i < 4; ++i) {
            int idx = tid + i * 256;
            int r = idx >> 4, kk = idx & 15;
            As[kk * LDSP + r] = A[(size_t)(bm + r) * lda + koff + k0 + kk];
            Ws[kk * LDSP + r] = W[(size_t)(bn + r) * ldw + koff + k0 + kk];
        }
        __syncthreads();
        #pragma unroll
        for (int kk = 0; kk < 16; ++kk) {
            float4 av = *reinterpret_cast<const float4*>(&As[kk * LDSP + ty * 4]);
            float4 bv = *reinterpret_cast<const float4*>(&Ws[kk * LDSP + tx * 4]);
            float a[4] = {av.x, av.y, av.z, av.w};
            float b[4] = {bv.x, bv.y, bv.z, bv.w};
            #pragma unroll
            for (int i = 0; i < 4; ++i)
                #pragma unroll
                for (int j = 0; j < 4; ++j)
                    acc[i][j] = fmaf(a[i], b[j], acc[i][j]);
        }
        __syncthreads();
    }

    float* base = Cpart + (size_t)blockIdx.z * M_ * 64;
    #pragma unroll
    for (int i = 0; i < 4; ++i) {
        int m = bm + ty * 4 + i;
        #pragma unroll
        for (int j = 0; j < 4; ++j) {
            int n = bn + tx * 4 + j;
            base[(size_t)m * 64 + n] = acc[i][j];
        }
    }
}

// sum KSPLIT partials -> xd, float4-vectorized
__global__ __launch_bounds__(256) void reduce_splitk(const float* __restrict__ Cpart,
                                                     float* __restrict__ xd) {
    int i = (blockIdx.x * 256 + threadIdx.x) * 4;   // over M_*64
    float4 a = *reinterpret_cast<const float4*>(Cpart + i);
    #pragma unroll
    for (int z = 1; z < KSPLIT; ++z) {
        float4 v = *reinterpret_cast<const float4*>(Cpart + (size_t)z * M_ * 64 + i);
        a.x += v.x; a.y += v.y; a.z += v.z; a.w += v.w;
    }
    *reinterpret_cast<float4*>(xd + i) = a;
}

// ---------------------------------------------------------------------------
// RMSNorm over last dim H_=512; writes bf16.
// ---------------------------------------------------------------------------
__global__ __launch_bounds__(256) void rms_norm_kernel(const float* __restrict__ h,
                                                       const float* __restrict__ w,
                                                       bf16_t* __restrict__ xnbf) {
    int row = blockIdx.x, tid = threadIdx.x;
    const float* hr = h + (size_t)row * H_;
    float v0 = hr[tid], v1 = hr[tid + 256];
    float s = v0 * v0 + v1 * v1;
    #pragma unroll
    for (int off = 32; off > 0; off >>= 1) s += __shfl_down(s, off);
    __shared__ float red[4];
    int wid = tid >> 6, lane = tid & 63;
    if (lane == 0) red[wid] = s;
    __syncthreads();
    float tot = red[0] + red[1] + red[2] + red[3];
    float sc = rsqrtf(tot * (1.f / H_) + RMS_EPS);
    xnbf[(size_t)row * H_ + tid]       = __float2bfloat16(v0 * sc * w[tid]);
    xnbf[(size_t)row * H_ + tid + 256] = __float2bfloat16(v1 * sc * w[tid + 256]);
}

// ---------------------------------------------------------------------------
// LayerNorm over last dim H_=512; writes bf16.
// ---------------------------------------------------------------------------
__global__ __launch_bounds__(256) void layer_norm_kernel(const float* __restrict__ h,
                                                         const float* __restrict__ g,
                                                         const float* __restrict__ bb,
                                                         bf16_t* __restrict__ out) {
    int row = blockIdx.x, tid = threadIdx.x;
    const float* hr = h + (size_t)row * H_;
    float v0 = hr[tid], v1 = hr[tid + 256];
    float s = v0 + v1;
    #pragma unroll
    for (int off = 32; off > 0; off >>= 1) s += __shfl_down(s, off);
    __shared__ float red[4];
    int wid = tid >> 6, lane = tid & 63;
    if (lane == 0) red[wid] = s;
    __syncthreads();
    float mu = (red[0] + red[1] + red[2] + red[3]) * (1.f / H_);
    __syncthreads();
    float d0 = v0 - mu, d1 = v1 - mu;
    float q = d0 * d0 + d1 * d1;
    #pragma unroll
    for (int off = 32; off > 0; off >>= 1) q += __shfl_down(q, off);
    if (lane == 0) red[wid] = q;
    __syncthreads();
    float var = (red[0] + red[1] + red[2] + red[3]) * (1.f / H_);
    float sc = rsqrtf(var + LN_EPS);
    out[(size_t)row * H_ + tid]       = __float2bfloat16(d0 * sc * g[tid]       + bb[tid]);
    out[(size_t)row * H_ + tid + 256] = __float2bfloat16(d1 * sc * g[tid + 256] + bb[tid + 256]);
}

// ---------------------------------------------------------------------------
// Causal depthwise conv (K=4, left-pad 3) + SiLU.
// ---------------------------------------------------------------------------
__global__ __launch_bounds__(256) void conv_silu_kernel(const float* __restrict__ xz,
                                                        const float* __restrict__ cw,
                                                        const float* __restrict__ cb,
                                                        float* __restrict__ u) {
    int idx = blockIdx.x * 256 + threadIdx.x;
    int c  = idx & (Di_ - 1);
    int bt = idx >> 10;
    int t  = bt & (T_ - 1);
    const float* base = xz + (size_t)bt * (2 * Di_) + c;
    float w0 = cw[c * KC_ + 0], w1 = cw[c * KC_ + 1];
    float w2 = cw[c * KC_ + 2], w3 = cw[c * KC_ + 3];
    float acc = cb[c];
    acc += base[0] * w3;
    if (t >= 1) acc += base[-(1 * 2 * Di_)] * w2;
    if (t >= 2) acc += base[-(2 * 2 * Di_)] * w1;
    if (t >= 3) acc += base[-(3 * 2 * Di_)] * w0;
    u[idx] = acc * (1.f / (1.f + __expf(-acc)));
}

// ---------------------------------------------------------------------------
// Chunked selective scan (3 passes). pass3 writes bf16 y (gated).
// ---------------------------------------------------------------------------
__global__ __launch_bounds__(256) void scan_pass1(const float* __restrict__ delta,
                                                  const float* __restrict__ u_in,
                                                  const float* __restrict__ xd,
                                                  const float* __restrict__ A_log,
                                                  float* __restrict__ aprod,
                                                  float* __restrict__ hend,
                                                  int NC, int CL) {
    __shared__ float bc[128 * 32];
    int blk = blockIdx.x;
    int g = blk & 3;
    int bk = blk >> 2;
    int k = bk % NC, b = bk / NC;
    int tid = threadIdx.x;
    int c = (g << 8) + tid;
    size_t bt0 = (size_t)b * T_ + (size_t)k * CL;

    for (int i = tid; i < CL * 32; i += 256) {
        int tt = i >> 5, j = i & 31;
        bc[i] = xd[(bt0 + tt) * 64 + 32 + j];
    }
    __syncthreads();

    float Ac[S_];
    #pragma unroll
    for (int s = 0; s < S_; ++s) Ac[s] = -__expf(A_log[c * S_ + s]);

    float h[S_] = {};
    float dsum = 0.f;
    for (int tt = 0; tt < CL; ++tt) {
        size_t bt = bt0 + tt;
        float d  = delta[bt * Di_ + c];
        float uu = u_in[bt * Di_ + c];
        float du = d * uu;
        dsum += d;
        #pragma unroll
        for (int s = 0; s < S_; ++s)
            h[s] = h[s] * __expf(d * Ac[s]) + du * bc[tt * 32 + s];
    }
    size_t pbase = ((size_t)(b * NC + k) * S_) * Di_ + c;
    #pragma unroll
    for (int s = 0; s < S_; ++s) {
        aprod[pbase + (size_t)s * Di_] = __expf(dsum * Ac[s]);
        hend [pbase + (size_t)s * Di_] = h[s];
    }
}

__global__ __launch_bounds__(256) void scan_pass2(const float* __restrict__ aprod,
                                                  float* __restrict__ hend,
                                                  int NC) {
    int gid = blockIdx.x * 256 + threadIdx.x;  // B*S*Di
    int c = gid & (Di_ - 1);
    int s = (gid >> 10) & (S_ - 1);
    int b = gid >> 14;
    float H = 0.f;
    for (int k = 0; k < NC; ++k) {
        size_t idx = ((size_t)(b * NC + k) * S_ + s) * Di_ + c;
        float pk = aprod[idx];
        float ek = hend[idx];
        hend[idx] = H;
        H = ek + pk * H;
    }
}

__global__ __launch_bounds__(256) void scan_pass3(const float* __restrict__ delta,
                                                  const float* __restrict__ u_in,
                                                  const float* __restrict__ xd,
                                                  const float* __restrict__ xz,
                                                  const float* __restrict__ A_log,
                                                  const float* __restrict__ D_ssm,
                                                  const float* __restrict__ hend,
                                                  bf16_t* __restrict__ ybf,
                                                  int NC, int CL) {
    __shared__ float bc[128 * 32];
    int blk = blockIdx.x;
    int g = blk & 3;
    int bk = blk >> 2;
    int k = bk % NC, b = bk / NC;
    int tid = threadIdx.x;
    int c = (g << 8) + tid;
    size_t bt0 = (size_t)b * T_ + (size_t)k * CL;

    for (int i = tid; i < CL * 32; i += 256) {
        int tt = i >> 5, j = i & 31;
        bc[i] = xd[(bt0 + tt) * 64 + 32 + j];
    }
    __syncthreads();

    float Ac[S_];
    #pragma unroll
    for (int s = 0; s < S_; ++s) Ac[s] = -__expf(A_log[c * S_ + s]);
    float Dp = D_ssm[c];

    float h[S_];
    size_t pbase = ((size_t)(b * NC + k) * S_) * Di_ + c;
    #pragma unroll
    for (int s = 0; s < S_; ++s) h[s] = hend[pbase + (size_t)s * Di_];

    for (int tt = 0; tt < CL; ++tt) {
        size_t bt = bt0 + tt;
        float d  = delta[bt * Di_ + c];
        float uu = u_in[bt * Di_ + c];
        float du = d * uu;
        float y = 0.f;
        #pragma unroll
        for (int s = 0; s < S_; ++s) {
            h[s] = h[s] * __expf(d * Ac[s]) + du * bc[tt * 32 + s];
            y = fmaf(h[s], bc[tt * 32 + 16 + s], y);
        }
        y += uu * Dp;
        float zz = xz[bt * (2 * Di_) + Di_ + c];
        float sig = 1.f / (1.f + __expf(-zz));
        ybf[bt * Di_ + c] = __float2bfloat16(y * (zz * sig));
    }
}

// ---------------------------------------------------------------------------
// Host launch
// ---------------------------------------------------------------------------
extern "C" void kernel_launch(void* const* d_in, const int* in_sizes, int n_in,
                              void* d_out, int out_size, void* d_ws, size_t ws_size,
                              hipStream_t stream) {
    const float* x         = (const float*)d_in[0];
    const float* in_w      = (const float*)d_in[1];
    const float* in_b      = (const float*)d_in[2];
    const float* rms_w     = (const float*)d_in[3];
    const float* in_proj_w = (const float*)d_in[4];
    const float* conv_w    = (const float*)d_in[5];
    const float* conv_b    = (const float*)d_in[6];
    const float* x_proj_w  = (const float*)d_in[7];
    const float* dt_proj_w = (const float*)d_in[8];
    const float* dt_proj_b = (const float*)d_in[9];
    const float* A_log     = (const float*)d_in[10];
    const float* D_ssm     = (const float*)d_in[11];
    const float* mb_out_w  = (const float*)d_in[12];
    const float* ln_g      = (const float*)d_in[13];
    const float* ln_b      = (const float*)d_in[14];
    const float* out_w     = (const float*)d_in[15];
    const float* out_b     = (const float*)d_in[16];

    float* ws = (float*)d_ws;
    float* h     = ws;
    float* xz    = h     + (size_t)M_ * H_;
    float* u     = xz    + (size_t)M_ * 2 * Di_;
    float* xd    = u     + (size_t)M_ * Di_;
    float* delta = xd    + (size_t)M_ * 64;
    float* mask  = delta + (size_t)M_ * Di_;
    bf16_t* xnbf  = (bf16_t*)(mask + M_);
    bf16_t* ybf   = xnbf  + (size_t)M_ * H_;
    bf16_t* xclbf = ybf   + (size_t)M_ * Di_;
    bf16_t* inwbf = xclbf + (size_t)M_ * IN_;
    bf16_t* ipwbf = inwbf + (size_t)H_ * IN_;
    bf16_t* owwbf = ipwbf + (size_t)L_ * 2 * Di_ * H_;
    bf16_t* outwbf= owwbf + (size_t)L_ * H_ * Di_;
    float* xdpart = (float*)(outwbf + (size_t)OUT_ * H_);   // KSPLIT*M*64
    float* aprod  = xdpart + (size_t)KSPLIT * M_ * 64;
    (void)n_in; (void)in_sizes; (void)out_size;

    size_t used = (size_t)(aprod - ws);
    size_t avail = (ws_size / 4 > used) ? ws_size / 4 - used : 0;
    int NC = 64;
    while (NC > 8 && 2 * (size_t)B_ * NC * S_ * Di_ > avail) NC >>= 1;
    int CL = T_ / NC;
    float* hend = aprod + (size_t)B_ * NC * S_ * Di_;

    // weight conversions (every call: deterministic)
    {
        int n;
        n = H_ * IN_;
        cvt_f32_bf16<<<(n / 4 + 255) / 256, 256, 0, stream>>>(in_w, inwbf, n);
        n = L_ * 2 * Di_ * H_;
        cvt_f32_bf16<<<(n / 4 + 255) / 256, 256, 0, stream>>>(in_proj_w, ipwbf, n);
        n = L_ * H_ * Di_;
        cvt_f32_bf16<<<(n / 4 + 255) / 256, 256, 0, stream>>>(mb_out_w, owwbf, n);
        n = OUT_ * H_;
        cvt_f32_bf16<<<(n / 4 + 255) / 256, 256, 0, stream>>>(out_w, outwbf, n);
    }

    // 1) nan handling
    prep_kernel<<<M_, 256, 0, stream>>>(x, xclbf, mask);

    // 2) h = (xclean @ in_w.T + in_b) * mask   [bf16 MFMA]
    gemm_bf16<false><<<dim3(H_ / 128, M_ / 128), 256, 0, stream>>>(
        xclbf, IN_, inwbf, IN_, h, H_, IN_, in_b, mask);

    for (int l = 0; l < L_; ++l) {
        const bf16_t* ipw = ipwbf + (size_t)l * 2 * Di_ * H_;
        const float* cwl = conv_w    + (size_t)l * Di_ * KC_;
        const float* cbl = conv_b    + (size_t)l * Di_;
        const float* xpw = x_proj_w  + (size_t)l * 64 * Di_;
        const float* dpw = dt_proj_w + (size_t)l * Di_ * R_;
        const float* dpb = dt_proj_b + (size_t)l * Di_;
        const float* Al  = A_log     + (size_t)l * Di_ * S_;
        const float* Dpl = D_ssm     + (size_t)l * Di_;
        const bf16_t* oww = owwbf + (size_t)l * H_ * Di_;
        const float* rwl = rms_w     + (size_t)l * H_;

        rms_norm_kernel<<<M_, 256, 0, stream>>>(h, rwl, xnbf);

        // xz = xn @ ipw.T   [bf16 MFMA]
        gemm_bf16<false><<<dim3(2 * Di_ / 128, M_ / 128), 256, 0, stream>>>(
            xnbf, H_, ipw, H_, xz, 2 * Di_, H_, nullptr, nullptr);

        conv_silu_kernel<<<(M_ * Di_) / 256, 256, 0, stream>>>(xz, cwl, cbl, u);

        // xd = u @ xpw.T  (f32 split-K: 512 blocks instead of 64)
        gemm_nt_splitk<<<dim3(1, M_ / 64, KSPLIT), 256, 0, stream>>>(
            u, Di_, xpw, Di_, xdpart, Di_ / KSPLIT);
        reduce_splitk<<<(M_ * 64 / 4) / 256, 256, 0, stream>>>(xdpart, xd);

        // delta = softplus(xd[:, :32] @ dpw.T + dpb)  (f32, K=32)
        gemm_nt<<<dim3(Di_ / 64, M_ / 64), 256, 0, stream>>>(
            xd, 64, dpw, R_, delta, Di_, R_, dpb, 1);

        // chunked scan
        scan_pass1<<<B_ * NC * (Di_ / 256), 256, 0, stream>>>(
            delta, u, xd, Al, aprod, hend, NC, CL);
        scan_pass2<<<(B_ * S_ * Di_) / 256, 256, 0, stream>>>(aprod, hend, NC);
        scan_pass3<<<B_ * NC * (Di_ / 256), 256, 0, stream>>>(
            delta, u, xd, xz, Al, Dpl, hend, ybf, NC, CL);

        // h += y @ oww.T   [bf16 MFMA, ACC]
        gemm_bf16<true><<<dim3(H_ / 128, M_ / 128), 256, 0, stream>>>(
            ybf, Di_, oww, Di_, h, H_, Di_, nullptr, nullptr);
    }

    layer_norm_kernel<<<M_, 256, 0, stream>>>(h, ln_g, ln_b, xnbf);

    gemm_bf16<false><<<dim3(OUT_ / 128, M_ / 128), 256, 0, stream>>>(
        xnbf, H_, outwbf, H_, (float*)d_out, OUT_, H_, out_b, nullptr);
}

// Round 5
// 665.099 us; speedup vs baseline: 9.2782x; 1.2455x over previous
//
#include <hip/hip_runtime.h>
#include <hip/hip_bf16.h>
#include <math.h>

// Problem constants
#define B_  4
#define T_  1024
#define IN_ 256
#define H_  512
#define L_  4
#define Di_ 1024
#define S_  16
#define R_  32
#define KC_ 4
#define OUT_ 256
#define M_  (B_*T_)          // 4096 rows everywhere
#define KSPLIT 8             // split-K factor for x_proj

#define RMS_EPS 1.1920929e-07f
#define LN_EPS  1e-05f

typedef __attribute__((ext_vector_type(8))) short  s16x8;   // 8 bf16
typedef __attribute__((ext_vector_type(4))) float  f32x4;
typedef __hip_bfloat16 bf16_t;

// ---------------------------------------------------------------------------
// f32 -> bf16 conversion (weights), 4 elems/thread
// ---------------------------------------------------------------------------
__global__ __launch_bounds__(256) void cvt_f32_bf16(const float* __restrict__ s,
                                                    bf16_t* __restrict__ d, int n) {
    int i = (blockIdx.x * 256 + threadIdx.x) * 4;
    if (i >= n) return;
    float4 v = *reinterpret_cast<const float4*>(s + i);
    d[i + 0] = __float2bfloat16(v.x);
    d[i + 1] = __float2bfloat16(v.y);
    d[i + 2] = __float2bfloat16(v.z);
    d[i + 3] = __float2bfloat16(v.w);
}

// ---------------------------------------------------------------------------
// prep: nan_to_num + per-row nan mask; writes bf16 xclean
// ---------------------------------------------------------------------------
__global__ __launch_bounds__(256) void prep_kernel(const float* __restrict__ x,
                                                   bf16_t* __restrict__ xclbf,
                                                   float* __restrict__ mask) {
    int row = blockIdx.x;
    int tid = threadIdx.x;
    float v = x[(size_t)row * IN_ + tid];
    int isn = isnan(v) ? 1 : 0;
    xclbf[(size_t)row * IN_ + tid] = __float2bfloat16(isn ? 0.f : v);
    __shared__ int f;
    if (tid == 0) f = 0;
    __syncthreads();
    if (isn) f = 1;
    __syncthreads();
    if (tid == 0) mask[row] = f ? 0.f : 1.f;
}

// ---------------------------------------------------------------------------
// bf16 MFMA GEMM: C[m,n] (+)= (A[m,:] . W[n,:] + bias[n]) * rowmask[m]
// BMxBN tile, BK=64, 256 thr = 4 waves (2x2), wave tile (BM/2)x(BN/2).
// LDS layout: [row][chunk] s16x8, chunk XOR-swizzled by (row&7).
// global_load_lds writes linearly; the inverse swizzle is applied to the
// per-lane GLOBAL source address; ds_read applies the same XOR (involution).
// Staging coalescing: 8 rows x 128B contiguous per wave-load.
// ds_read banks: 8 distinct 16B slots per 8-row stripe -> 2-way (free).
// ---------------------------------------------------------------------------
template<int BM, int BN, bool ACC>
__global__ __launch_bounds__(256) void gemm_bf16(const bf16_t* __restrict__ A, int lda,
                                                 const bf16_t* __restrict__ W, int ldw,
                                                 float* __restrict__ C, int ldc,
                                                 int K,
                                                 const float* __restrict__ bias,
                                                 const float* __restrict__ rowmask) {
    constexpr int MF = BM / 32;      // m-frags per wave
    constexpr int NF = BN / 32;      // n-frags per wave
    __shared__ s16x8 As[BM * 8];
    __shared__ s16x8 Ws[BN * 8];
    const int bm = blockIdx.y * BM;
    const int bn = blockIdx.x * BN;
    const int tid  = threadIdx.x;
    const int lane = tid & 63;
    const int w    = tid >> 6;
    const int wr   = w >> 1;
    const int wc   = w & 1;

    f32x4 acc[MF][NF] = {};

    for (int k0 = 0; k0 < K; k0 += 64) {
        // stage A tile: BM*8 slots, 256 slots/iter
        #pragma unroll
        for (int i = 0; i < BM / 32; ++i) {
            int gbase = i * 256 + w * 64;          // wave-uniform LDS slot base
            int g = gbase + lane;
            int row = g >> 3, ch = g & 7;
            int cg = ch ^ (row & 7);               // inverse swizzle on source
            const bf16_t* sA = A + (size_t)(bm + row) * lda + k0 + cg * 8;
            __builtin_amdgcn_global_load_lds(
                (const __attribute__((address_space(1))) void*)sA,
                (__attribute__((address_space(3))) void*)((char*)As + gbase * 16),
                16, 0, 0);
        }
        // stage W tile
        #pragma unroll
        for (int i = 0; i < BN / 32; ++i) {
            int gbase = i * 256 + w * 64;
            int g = gbase + lane;
            int row = g >> 3, ch = g & 7;
            int cg = ch ^ (row & 7);
            const bf16_t* sW = W + (size_t)(bn + row) * ldw + k0 + cg * 8;
            __builtin_amdgcn_global_load_lds(
                (const __attribute__((address_space(1))) void*)sW,
                (__attribute__((address_space(3))) void*)((char*)Ws + gbase * 16),
                16, 0, 0);
        }
        __syncthreads();

        #pragma unroll
        for (int ks = 0; ks < 2; ++ks) {
            const int ck = ks * 4 + (lane >> 4);   // logical k-chunk 0..7
            const int arow = wr * (BM / 2) + (lane & 15);
            const int brow = wc * (BN / 2) + (lane & 15);
            const int axor = ck ^ (arow & 7);
            const int bxor = ck ^ (brow & 7);
            s16x8 af[MF], bfr[NF];
            #pragma unroll
            for (int f = 0; f < MF; ++f)
                af[f] = As[(arow + f * 16) * 8 + axor];
            #pragma unroll
            for (int f = 0; f < NF; ++f)
                bfr[f] = Ws[(brow + f * 16) * 8 + bxor];
            #pragma unroll
            for (int mf = 0; mf < MF; ++mf)
                #pragma unroll
                for (int nf = 0; nf < NF; ++nf)
                    acc[mf][nf] = __builtin_amdgcn_mfma_f32_16x16x32_bf16(
                        af[mf], bfr[nf], acc[mf][nf], 0, 0, 0);
        }
        __syncthreads();
    }

    // epilogue: C/D frag layout col=lane&15, row=(lane>>4)*4+reg
    #pragma unroll
    for (int mf = 0; mf < MF; ++mf) {
        int rbase = bm + wr * (BM / 2) + mf * 16 + ((lane >> 4) << 2);
        #pragma unroll
        for (int nf = 0; nf < NF; ++nf) {
            int n = bn + wc * (BN / 2) + nf * 16 + (lane & 15);
            float bv = bias ? bias[n] : 0.f;
            #pragma unroll
            for (int r = 0; r < 4; ++r) {
                int m = rbase + r;
                float v = acc[mf][nf][r] + bv;
                if (rowmask) v *= rowmask[m];
                float* p = &C[(size_t)m * ldc + n];
                if (ACC) v += *p;
                *p = v;
            }
        }
    }
}

// ---------------------------------------------------------------------------
// Generic f32 GEMM (dt_proj). 64x64 tile, BK=16. act: 0=none, 1=softplus
// ---------------------------------------------------------------------------
#define LDSP 68
__global__ __launch_bounds__(256) void gemm_nt(const float* __restrict__ A, int lda,
                                               const float* __restrict__ W, int ldw,
                                               float* __restrict__ C, int ldc,
                                               int K,
                                               const float* __restrict__ bias,
                                               int act) {
    __shared__ float As[16 * LDSP];
    __shared__ float Ws[16 * LDSP];
    const int bm = blockIdx.y * 64;
    const int bn = blockIdx.x * 64;
    const int tid = threadIdx.x;
    const int ty = tid >> 4;
    const int tx = tid & 15;

    float acc[4][4] = {};

    for (int k0 = 0; k0 < K; k0 += 16) {
        #pragma unroll
        for (int i = 0; i < 4; ++i) {
            int idx = tid + i * 256;
            int r = idx >> 4, kk = idx & 15;
            As[kk * LDSP + r] = A[(size_t)(bm + r) * lda + k0 + kk];
            Ws[kk * LDSP + r] = W[(size_t)(bn + r) * ldw + k0 + kk];
        }
        __syncthreads();
        #pragma unroll
        for (int kk = 0; kk < 16; ++kk) {
            float4 av = *reinterpret_cast<const float4*>(&As[kk * LDSP + ty * 4]);
            float4 bv = *reinterpret_cast<const float4*>(&Ws[kk * LDSP + tx * 4]);
            float a[4] = {av.x, av.y, av.z, av.w};
            float b[4] = {bv.x, bv.y, bv.z, bv.w};
            #pragma unroll
            for (int i = 0; i < 4; ++i)
                #pragma unroll
                for (int j = 0; j < 4; ++j)
                    acc[i][j] = fmaf(a[i], b[j], acc[i][j]);
        }
        __syncthreads();
    }

    #pragma unroll
    for (int i = 0; i < 4; ++i) {
        int m = bm + ty * 4 + i;
        #pragma unroll
        for (int j = 0; j < 4; ++j) {
            int n = bn + tx * 4 + j;
            float v = acc[i][j];
            if (bias) v += bias[n];
            if (act == 1) v = (v > 20.f) ? v : log1pf(__expf(v));
            C[(size_t)m * ldc + n] = v;
        }
    }
}

// ---------------------------------------------------------------------------
// Split-K f32 GEMM for x_proj: N=64, ldc=64, no bias/act.
// ---------------------------------------------------------------------------
__global__ __launch_bounds__(256) void gemm_nt_splitk(const float* __restrict__ A, int lda,
                                                      const float* __restrict__ W, int ldw,
                                                      float* __restrict__ Cpart,
                                                      int Kchunk) {
    __shared__ float As[16 * LDSP];
    __shared__ float Ws[16 * LDSP];
    const int bm = blockIdx.y * 64;
    const int bn = blockIdx.x * 64;
    const int koff = blockIdx.z * Kchunk;
    const int tid = threadIdx.x;
    const int ty = tid >> 4;
    const int tx = tid & 15;

    float acc[4][4] = {};

    for (int k0 = 0; k0 < Kchunk; k0 += 16) {
        #pragma unroll
        for (int i = 0; i < 4; ++i) {
            int idx = tid + i * 256;
            int r = idx >> 4, kk = idx & 15;
            As[kk * LDSP + r] = A[(size_t)(bm + r) * lda + koff + k0 + kk];
            Ws[kk * LDSP + r] = W[(size_t)(bn + r) * ldw + koff + k0 + kk];
        }
        __syncthreads();
        #pragma unroll
        for (int kk = 0; kk < 16; ++kk) {
            float4 av = *reinterpret_cast<const float4*>(&As[kk * LDSP + ty * 4]);
            float4 bv = *reinterpret_cast<const float4*>(&Ws[kk * LDSP + tx * 4]);
            float a[4] = {av.x, av.y, av.z, av.w};
            float b[4] = {bv.x, bv.y, bv.z, bv.w};
            #pragma unroll
            for (int i = 0; i < 4; ++i)
                #pragma unroll
                for (int j = 0; j < 4; ++j)
                    acc[i][j] = fmaf(a[i], b[j], acc[i][j]);
        }
        __syncthreads();
    }

    float* base = Cpart + (size_t)blockIdx.z * M_ * 64;
    #pragma unroll
    for (int i = 0; i < 4; ++i) {
        int m = bm + ty * 4 + i;
        #pragma unroll
        for (int j = 0; j < 4; ++j) {
            int n = bn + tx * 4 + j;
            base[(size_t)m * 64 + n] = acc[i][j];
        }
    }
}

// sum KSPLIT partials -> xd, float4-vectorized
__global__ __launch_bounds__(256) void reduce_splitk(const float* __restrict__ Cpart,
                                                     float* __restrict__ xd) {
    int i = (blockIdx.x * 256 + threadIdx.x) * 4;   // over M_*64
    float4 a = *reinterpret_cast<const float4*>(Cpart + i);
    #pragma unroll
    for (int z = 1; z < KSPLIT; ++z) {
        float4 v = *reinterpret_cast<const float4*>(Cpart + (size_t)z * M_ * 64 + i);
        a.x += v.x; a.y += v.y; a.z += v.z; a.w += v.w;
    }
    *reinterpret_cast<float4*>(xd + i) = a;
}

// ---------------------------------------------------------------------------
// RMSNorm over last dim H_=512; writes bf16.
// ---------------------------------------------------------------------------
__global__ __launch_bounds__(256) void rms_norm_kernel(const float* __restrict__ h,
                                                       const float* __restrict__ w,
                                                       bf16_t* __restrict__ xnbf) {
    int row = blockIdx.x, tid = threadIdx.x;
    const float* hr = h + (size_t)row * H_;
    float v0 = hr[tid], v1 = hr[tid + 256];
    float s = v0 * v0 + v1 * v1;
    #pragma unroll
    for (int off = 32; off > 0; off >>= 1) s += __shfl_down(s, off);
    __shared__ float red[4];
    int wid = tid >> 6, lane = tid & 63;
    if (lane == 0) red[wid] = s;
    __syncthreads();
    float tot = red[0] + red[1] + red[2] + red[3];
    float sc = rsqrtf(tot * (1.f / H_) + RMS_EPS);
    xnbf[(size_t)row * H_ + tid]       = __float2bfloat16(v0 * sc * w[tid]);
    xnbf[(size_t)row * H_ + tid + 256] = __float2bfloat16(v1 * sc * w[tid + 256]);
}

// ---------------------------------------------------------------------------
// LayerNorm over last dim H_=512; writes bf16.
// ---------------------------------------------------------------------------
__global__ __launch_bounds__(256) void layer_norm_kernel(const float* __restrict__ h,
                                                         const float* __restrict__ g,
                                                         const float* __restrict__ bb,
                                                         bf16_t* __restrict__ out) {
    int row = blockIdx.x, tid = threadIdx.x;
    const float* hr = h + (size_t)row * H_;
    float v0 = hr[tid], v1 = hr[tid + 256];
    float s = v0 + v1;
    #pragma unroll
    for (int off = 32; off > 0; off >>= 1) s += __shfl_down(s, off);
    __shared__ float red[4];
    int wid = tid >> 6, lane = tid & 63;
    if (lane == 0) red[wid] = s;
    __syncthreads();
    float mu = (red[0] + red[1] + red[2] + red[3]) * (1.f / H_);
    __syncthreads();
    float d0 = v0 - mu, d1 = v1 - mu;
    float q = d0 * d0 + d1 * d1;
    #pragma unroll
    for (int off = 32; off > 0; off >>= 1) q += __shfl_down(q, off);
    if (lane == 0) red[wid] = q;
    __syncthreads();
    float var = (red[0] + red[1] + red[2] + red[3]) * (1.f / H_);
    float sc = rsqrtf(var + LN_EPS);
    out[(size_t)row * H_ + tid]       = __float2bfloat16(d0 * sc * g[tid]       + bb[tid]);
    out[(size_t)row * H_ + tid + 256] = __float2bfloat16(d1 * sc * g[tid + 256] + bb[tid + 256]);
}

// ---------------------------------------------------------------------------
// Causal depthwise conv (K=4, left-pad 3) + SiLU.
// ---------------------------------------------------------------------------
__global__ __launch_bounds__(256) void conv_silu_kernel(const float* __restrict__ xz,
                                                        const float* __restrict__ cw,
                                                        const float* __restrict__ cb,
                                                        float* __restrict__ u) {
    int idx = blockIdx.x * 256 + threadIdx.x;
    int c  = idx & (Di_ - 1);
    int bt = idx >> 10;
    int t  = bt & (T_ - 1);
    const float* base = xz + (size_t)bt * (2 * Di_) + c;
    float w0 = cw[c * KC_ + 0], w1 = cw[c * KC_ + 1];
    float w2 = cw[c * KC_ + 2], w3 = cw[c * KC_ + 3];
    float acc = cb[c];
    acc += base[0] * w3;
    if (t >= 1) acc += base[-(1 * 2 * Di_)] * w2;
    if (t >= 2) acc += base[-(2 * 2 * Di_)] * w1;
    if (t >= 3) acc += base[-(3 * 2 * Di_)] * w0;
    u[idx] = acc * (1.f / (1.f + __expf(-acc)));
}

// ---------------------------------------------------------------------------
// Chunked selective scan (3 passes). pass3 writes bf16 y (gated).
// ---------------------------------------------------------------------------
__global__ __launch_bounds__(256) void scan_pass1(const float* __restrict__ delta,
                                                  const float* __restrict__ u_in,
                                                  const float* __restrict__ xd,
                                                  const float* __restrict__ A_log,
                                                  float* __restrict__ aprod,
                                                  float* __restrict__ hend,
                                                  int NC, int CL) {
    __shared__ float bc[128 * 32];
    int blk = blockIdx.x;
    int g = blk & 3;
    int bk = blk >> 2;
    int k = bk % NC, b = bk / NC;
    int tid = threadIdx.x;
    int c = (g << 8) + tid;
    size_t bt0 = (size_t)b * T_ + (size_t)k * CL;

    for (int i = tid; i < CL * 32; i += 256) {
        int tt = i >> 5, j = i & 31;
        bc[i] = xd[(bt0 + tt) * 64 + 32 + j];
    }
    __syncthreads();

    float Ac[S_];
    #pragma unroll
    for (int s = 0; s < S_; ++s) Ac[s] = -__expf(A_log[c * S_ + s]);

    float h[S_] = {};
    float dsum = 0.f;
    for (int tt = 0; tt < CL; ++tt) {
        size_t bt = bt0 + tt;
        float d  = delta[bt * Di_ + c];
        float uu = u_in[bt * Di_ + c];
        float du = d * uu;
        dsum += d;
        #pragma unroll
        for (int s = 0; s < S_; ++s)
            h[s] = h[s] * __expf(d * Ac[s]) + du * bc[tt * 32 + s];
    }
    size_t pbase = ((size_t)(b * NC + k) * S_) * Di_ + c;
    #pragma unroll
    for (int s = 0; s < S_; ++s) {
        aprod[pbase + (size_t)s * Di_] = __expf(dsum * Ac[s]);
        hend [pbase + (size_t)s * Di_] = h[s];
    }
}

__global__ __launch_bounds__(256) void scan_pass2(const float* __restrict__ aprod,
                                                  float* __restrict__ hend,
                                                  int NC) {
    int gid = blockIdx.x * 256 + threadIdx.x;  // B*S*Di
    int c = gid & (Di_ - 1);
    int s = (gid >> 10) & (S_ - 1);
    int b = gid >> 14;
    float H = 0.f;
    for (int k = 0; k < NC; ++k) {
        size_t idx = ((size_t)(b * NC + k) * S_ + s) * Di_ + c;
        float pk = aprod[idx];
        float ek = hend[idx];
        hend[idx] = H;
        H = ek + pk * H;
    }
}

__global__ __launch_bounds__(256) void scan_pass3(const float* __restrict__ delta,
                                                  const float* __restrict__ u_in,
                                                  const float* __restrict__ xd,
                                                  const float* __restrict__ xz,
                                                  const float* __restrict__ A_log,
                                                  const float* __restrict__ D_ssm,
                                                  const float* __restrict__ hend,
                                                  bf16_t* __restrict__ ybf,
                                                  int NC, int CL) {
    __shared__ float bc[128 * 32];
    int blk = blockIdx.x;
    int g = blk & 3;
    int bk = blk >> 2;
    int k = bk % NC, b = bk / NC;
    int tid = threadIdx.x;
    int c = (g << 8) + tid;
    size_t bt0 = (size_t)b * T_ + (size_t)k * CL;

    for (int i = tid; i < CL * 32; i += 256) {
        int tt = i >> 5, j = i & 31;
        bc[i] = xd[(bt0 + tt) * 64 + 32 + j];
    }
    __syncthreads();

    float Ac[S_];
    #pragma unroll
    for (int s = 0; s < S_; ++s) Ac[s] = -__expf(A_log[c * S_ + s]);
    float Dp = D_ssm[c];

    float h[S_];
    size_t pbase = ((size_t)(b * NC + k) * S_) * Di_ + c;
    #pragma unroll
    for (int s = 0; s < S_; ++s) h[s] = hend[pbase + (size_t)s * Di_];

    for (int tt = 0; tt < CL; ++tt) {
        size_t bt = bt0 + tt;
        float d  = delta[bt * Di_ + c];
        float uu = u_in[bt * Di_ + c];
        float du = d * uu;
        float y = 0.f;
        #pragma unroll
        for (int s = 0; s < S_; ++s) {
            h[s] = h[s] * __expf(d * Ac[s]) + du * bc[tt * 32 + s];
            y = fmaf(h[s], bc[tt * 32 + 16 + s], y);
        }
        y += uu * Dp;
        float zz = xz[bt * (2 * Di_) + Di_ + c];
        float sig = 1.f / (1.f + __expf(-zz));
        ybf[bt * Di_ + c] = __float2bfloat16(y * (zz * sig));
    }
}

// ---------------------------------------------------------------------------
// Host launch
// ---------------------------------------------------------------------------
extern "C" void kernel_launch(void* const* d_in, const int* in_sizes, int n_in,
                              void* d_out, int out_size, void* d_ws, size_t ws_size,
                              hipStream_t stream) {
    const float* x         = (const float*)d_in[0];
    const float* in_w      = (const float*)d_in[1];
    const float* in_b      = (const float*)d_in[2];
    const float* rms_w     = (const float*)d_in[3];
    const float* in_proj_w = (const float*)d_in[4];
    const float* conv_w    = (const float*)d_in[5];
    const float* conv_b    = (const float*)d_in[6];
    const float* x_proj_w  = (const float*)d_in[7];
    const float* dt_proj_w = (const float*)d_in[8];
    const float* dt_proj_b = (const float*)d_in[9];
    const float* A_log     = (const float*)d_in[10];
    const float* D_ssm     = (const float*)d_in[11];
    const float* mb_out_w  = (const float*)d_in[12];
    const float* ln_g      = (const float*)d_in[13];
    const float* ln_b      = (const float*)d_in[14];
    const float* out_w     = (const float*)d_in[15];
    const float* out_b     = (const float*)d_in[16];

    float* ws = (float*)d_ws;
    float* h     = ws;
    float* xz    = h     + (size_t)M_ * H_;
    float* u     = xz    + (size_t)M_ * 2 * Di_;
    float* xd    = u     + (size_t)M_ * Di_;
    float* delta = xd    + (size_t)M_ * 64;
    float* mask  = delta + (size_t)M_ * Di_;
    bf16_t* xnbf  = (bf16_t*)(mask + M_);
    bf16_t* ybf   = xnbf  + (size_t)M_ * H_;
    bf16_t* xclbf = ybf   + (size_t)M_ * Di_;
    bf16_t* inwbf = xclbf + (size_t)M_ * IN_;
    bf16_t* ipwbf = inwbf + (size_t)H_ * IN_;
    bf16_t* owwbf = ipwbf + (size_t)L_ * 2 * Di_ * H_;
    bf16_t* outwbf= owwbf + (size_t)L_ * H_ * Di_;
    float* xdpart = (float*)(outwbf + (size_t)OUT_ * H_);   // KSPLIT*M*64
    float* aprod  = xdpart + (size_t)KSPLIT * M_ * 64;
    (void)n_in; (void)in_sizes; (void)out_size;

    size_t used = (size_t)(aprod - ws);
    size_t avail = (ws_size / 4 > used) ? ws_size / 4 - used : 0;
    int NC = 64;
    while (NC > 8 && 2 * (size_t)B_ * NC * S_ * Di_ > avail) NC >>= 1;
    int CL = T_ / NC;
    float* hend = aprod + (size_t)B_ * NC * S_ * Di_;

    // weight conversions (every call: deterministic)
    {
        int n;
        n = H_ * IN_;
        cvt_f32_bf16<<<(n / 4 + 255) / 256, 256, 0, stream>>>(in_w, inwbf, n);
        n = L_ * 2 * Di_ * H_;
        cvt_f32_bf16<<<(n / 4 + 255) / 256, 256, 0, stream>>>(in_proj_w, ipwbf, n);
        n = L_ * H_ * Di_;
        cvt_f32_bf16<<<(n / 4 + 255) / 256, 256, 0, stream>>>(mb_out_w, owwbf, n);
        n = OUT_ * H_;
        cvt_f32_bf16<<<(n / 4 + 255) / 256, 256, 0, stream>>>(out_w, outwbf, n);
    }

    // 1) nan handling
    prep_kernel<<<M_, 256, 0, stream>>>(x, xclbf, mask);

    // 2) h = (xclean @ in_w.T + in_b) * mask   [bf16 MFMA, 64x64 -> 512 blocks]
    gemm_bf16<64, 64, false><<<dim3(H_ / 64, M_ / 64), 256, 0, stream>>>(
        xclbf, IN_, inwbf, IN_, h, H_, IN_, in_b, mask);

    for (int l = 0; l < L_; ++l) {
        const bf16_t* ipw = ipwbf + (size_t)l * 2 * Di_ * H_;
        const float* cwl = conv_w    + (size_t)l * Di_ * KC_;
        const float* cbl = conv_b    + (size_t)l * Di_;
        const float* xpw = x_proj_w  + (size_t)l * 64 * Di_;
        const float* dpw = dt_proj_w + (size_t)l * Di_ * R_;
        const float* dpb = dt_proj_b + (size_t)l * Di_;
        const float* Al  = A_log     + (size_t)l * Di_ * S_;
        const float* Dpl = D_ssm     + (size_t)l * Di_;
        const bf16_t* oww = owwbf + (size_t)l * H_ * Di_;
        const float* rwl = rms_w     + (size_t)l * H_;

        rms_norm_kernel<<<M_, 256, 0, stream>>>(h, rwl, xnbf);

        // xz = xn @ ipw.T   [bf16 MFMA, 128x128 -> 512 blocks]
        gemm_bf16<128, 128, false><<<dim3(2 * Di_ / 128, M_ / 128), 256, 0, stream>>>(
            xnbf, H_, ipw, H_, xz, 2 * Di_, H_, nullptr, nullptr);

        conv_silu_kernel<<<(M_ * Di_) / 256, 256, 0, stream>>>(xz, cwl, cbl, u);

        // xd = u @ xpw.T  (f32 split-K)
        gemm_nt_splitk<<<dim3(1, M_ / 64, KSPLIT), 256, 0, stream>>>(
            u, Di_, xpw, Di_, xdpart, Di_ / KSPLIT);
        reduce_splitk<<<(M_ * 64 / 4) / 256, 256, 0, stream>>>(xdpart, xd);

        // delta = softplus(xd[:, :32] @ dpw.T + dpb)  (f32, K=32)
        gemm_nt<<<dim3(Di_ / 64, M_ / 64), 256, 0, stream>>>(
            xd, 64, dpw, R_, delta, Di_, R_, dpb, 1);

        // chunked scan
        scan_pass1<<<B_ * NC * (Di_ / 256), 256, 0, stream>>>(
            delta, u, xd, Al, aprod, hend, NC, CL);
        scan_pass2<<<(B_ * S_ * Di_) / 256, 256, 0, stream>>>(aprod, hend, NC);
        scan_pass3<<<B_ * NC * (Di_ / 256), 256, 0, stream>>>(
            delta, u, xd, xz, Al, Dpl, hend, ybf, NC, CL);

        // h += y @ oww.T   [bf16 MFMA ACC, 64x64 -> 512 blocks]
        gemm_bf16<64, 64, true><<<dim3(H_ / 64, M_ / 64), 256, 0, stream>>>(
            ybf, Di_, oww, Di_, h, H_, Di_, nullptr, nullptr);
    }

    layer_norm_kernel<<<M_, 256, 0, stream>>>(h, ln_g, ln_b, xnbf);

    // out GEMM: 64x64 -> 256 blocks
    gemm_bf16<64, 64, false><<<dim3(OUT_ / 64, M_ / 64), 256, 0, stream>>>(
        xnbf, H_, outwbf, H_, (float*)d_out, OUT_, H_, out_b, nullptr);
}